// Round 2
// baseline (110048.096 us; speedup 1.0000x reference)
//
#include <hip/hip_runtime.h>
#include <hip/hip_bf16.h>

typedef unsigned int uint32;
typedef unsigned short u16;

#define H    768
#define H2   1536
#define H3   2304
#define H6   4608
#define BB   8
#define SS   128
#define GG   1024
#define NWG  256
#define NT   256
#define INVSCALE 0.036084391824351615f
#define SPIN_LIMIT (1 << 21)
#define DYN_LDS 163072

struct IN {
  const int *chat_ids, *speaker_info, *inputs;
  const float *emb, *d_wih, *d_whh, *d_bih, *d_bhh;
  const float *g_wih, *g_whh, *g_bih, *g_bhh;
  const float *s_wih, *s_whh, *s_bih, *s_bhh;
  const float *wq, *bq, *wk, *bk, *wv, *bv;
  const float *h0, *d_h0, *attn_h;
};

struct WS {
  int *flags1, *flags2;
  float *Mqk, *Gsum;
  float *cu, *vkq, *cb, *cvs, *ch0s, *cvg, *chg0, *ghs0;
  float *Ms, *Mg;              // f32 precomputed attn-folded matrices
  float *gi_d, *GIS;           // aliased region (gi_d dead before GIS written)
  float *dialogue, *U, *cvec, *GIG;
  float *gh_dbuf;              // [2][BB][H3] rnnD double buffer
  float *sp_global;            // [8][H2] speaker states (single authority)
  float *op_buf;
  float *gi_attn, *gh_s2, *gh_g2, *gig_w2, *gig_h, *scores_buf, *probs_buf;
  float *h_buf, *Wbuf, *AO;
  float *out_op, *out_spop;
};

__device__ inline float sigm(float x) { return 1.f / (1.f + expf(-x)); }

__device__ inline u16 f2bf(float v) {
  __hip_bfloat16 b = __float2bfloat16(v);
  return *reinterpret_cast<u16*>(&b);
}

// ---- device-scope grid barrier (NWG WGs, 1 per CU) ----
__device__ inline void gbar(int* flags, int epoch, int& dead) {
  int bail = 0;
  __syncthreads();
  if (!dead) {
    __threadfence();  // release
    if (threadIdx.x == 0)
      __hip_atomic_store(&flags[blockIdx.x], epoch, __ATOMIC_RELAXED, __HIP_MEMORY_SCOPE_AGENT);
    int spins = 0;
    while (__hip_atomic_load(&flags[threadIdx.x], __ATOMIC_RELAXED, __HIP_MEMORY_SCOPE_AGENT) < epoch) {
      if (++spins > SPIN_LIMIT) { bail = 1; break; }
    }
  }
  dead |= __syncthreads_or(bail);
  __threadfence();  // acquire
  __syncthreads();
}

// ---- per-wave dot: one output column, bf16 weights (LDS), f32 x (LDS or global) ----
template <int K>
__device__ inline float dot_bf(const u16* wcol, const float* x) {
  const uint32* wp = (const uint32*)wcol;
  int l = threadIdx.x & 63;
  float acc = 0.f;
  #pragma unroll
  for (int i = 0; i < K / 128; i++) {
    int idx = i * 64 + l;
    uint32 u = wp[idx];
    float2 xv = *(const float2*)(x + 2 * idx);
    acc = fmaf(xv.x, __uint_as_float(u << 16),
          fmaf(xv.y, __uint_as_float(u & 0xffff0000u), acc));
  }
  #pragma unroll
  for (int o = 32; o > 0; o >>= 1) acc += __shfl_down(acc, o);
  return acc;  // valid on lane 0
}

// ================= prep kernels =================

__global__ __launch_bounds__(NT) void prep1_k(IN in, WS w) {
  long i = (long)blockIdx.x * NT + threadIdx.x;
  const long NG = (long)H3 * H;
  if (i < NG) {
    long n = i / H, k = i - n * H;
    w.Gsum[i] = in.g_wih[n * H3 + H + k] + in.g_wih[n * H3 + 2 * H + k];
  } else if (i < NG + H) {
    int m = (int)(i - NG);
    float a = 0.f;
    for (int t = 0; t < H; t++) a = fmaf(in.bq[t], in.wk[(long)t * H + m], a);
    w.cu[m] = a;
  } else if (i < NG + 2 * H) {
    int m = (int)(i - NG - H);
    float a = 0.f;
    for (int t = 0; t < H; t++) a = fmaf(in.bk[t], in.wq[(long)t * H + m], a);
    w.vkq[m] = a;
  } else if (i == NG + 2 * H) {
    float a = 0.f;
    for (int t = 0; t < H; t++) a = fmaf(in.bk[t], in.bq[t], a);
    w.cb[0] = a;
  }
}

__global__ __launch_bounds__(NT) void prep2_k(IN in, WS w) {
  int i = blockIdx.x * NT + threadIdx.x;
  if (i < H6) {
    const float* row = in.s_wih + (long)i * H2;
    float a = 0.f, c = 0.f;
    for (int t = 0; t < H; t++) { a = fmaf(in.bv[t], row[t], a); c = fmaf(in.attn_h[t], row[t], c); }
    w.cvs[i] = a; w.ch0s[i] = c;
  } else if (i < H6 + H3) {
    int k = i - H6;
    const float* row = in.g_wih + (long)k * H3;
    float a = 0.f, c = 0.f;
    for (int t = 0; t < H; t++) { a = fmaf(in.bv[t], row[t], a); c = fmaf(in.attn_h[t], row[t], c); }
    w.cvg[k] = a; w.chg0[k] = c;
  } else if (i < H6 + H3 + H6) {
    int k = i - H6 - H3;
    const float* row = in.s_whh + (long)k * H2;
    float a = in.s_bhh[k];
    for (int t = 0; t < H2; t++) a = fmaf(in.h0[t], row[t], a);
    w.ghs0[k] = a;
  }
}

// ---- generic f32 GEMM: C[M][N] = A[M][K]*B[K][N] (+bias); strided, optional gather ----
__global__ __launch_bounds__(NT) void gemm_k(const float* A, long sAm, long sAk, const int* gather,
                                             const float* B, long sBk, long sBn,
                                             const float* bias, float* C,
                                             int M, int N, int K) {
  __shared__ float As[16][65];
  __shared__ float Bs[16][65];
  int m0 = blockIdx.y * 64, n0 = blockIdx.x * 64;
  int tid = threadIdx.x;
  int tx = tid & 15, ty = tid >> 4;
  float acc[4][4] = {};
  for (int k0 = 0; k0 < K; k0 += 16) {
    if (sAk == 1) {
      int k = tid & 15, mb = tid >> 4;
      for (int p = 0; p < 4; p++) {
        int m = mb + p * 16;
        long row = gather ? (long)gather[m0 + m] : (long)(m0 + m);
        As[k][m] = A[row * sAm + (k0 + k)];
      }
    } else {
      int m = tid & 63, kb = tid >> 6;
      for (int p = 0; p < 4; p++) {
        int k = kb + p * 4;
        long row = gather ? (long)gather[m0 + m] : (long)(m0 + m);
        As[k][m] = A[row * sAm + (long)(k0 + k) * sAk];
      }
    }
    if (sBn == 1) {
      int n = tid & 63, kb = tid >> 6;
      for (int p = 0; p < 4; p++) {
        int k = kb + p * 4;
        Bs[k][n] = B[(long)(k0 + k) * sBk + (n0 + n)];
      }
    } else {
      int k = tid & 15, nb = tid >> 4;
      for (int p = 0; p < 4; p++) {
        int n = nb + p * 16;
        Bs[k][n] = B[(long)(k0 + k) + (long)(n0 + n) * sBn];
      }
    }
    __syncthreads();
    #pragma unroll
    for (int k = 0; k < 16; k++) {
      float a[4], b[4];
      #pragma unroll
      for (int i = 0; i < 4; i++) a[i] = As[k][ty * 4 + i];
      #pragma unroll
      for (int j = 0; j < 4; j++) b[j] = Bs[k][tx * 4 + j];
      #pragma unroll
      for (int i = 0; i < 4; i++)
        #pragma unroll
        for (int j = 0; j < 4; j++) acc[i][j] = fmaf(a[i], b[j], acc[i][j]);
    }
    __syncthreads();
  }
  for (int i = 0; i < 4; i++)
    for (int j = 0; j < 4; j++) {
      int m = m0 + ty * 4 + i, n = n0 + tx * 4 + j;
      C[(long)m * N + n] = acc[i][j] + (bias ? bias[n] : 0.f);
    }
}

// ================= sequential kernels =================

__global__ __launch_bounds__(NT) void coop_rnnD(IN in, WS w) {
  __shared__ u16 wD[9 * H];
  __shared__ float hB[BB][H];
  int tid = threadIdx.x, wg = blockIdx.x;
  int c0 = wg * 9;
  for (int i = tid; i < 9 * H; i += NT)
    wD[i] = f2bf(in.d_whh[(long)(c0 + i / H) * H + (i % H)]);
  __syncthreads();
  int epoch = 1, dead = 0;
  int l = tid & 63, wv = tid >> 6;
  for (int t = 0; t < SS; t++) {
    if (t > 0) {
      float* ghb = w.gh_dbuf + (size_t)(t & 1) * BB * H3;
      for (int j2 = 0; j2 < 18; j2++) {
        int b = wv * 2 + (j2 >= 9 ? 1 : 0), j = j2 % 9;
        float val = dot_bf<H>(wD + j * H, hB[b]);
        if (l == 0) ghb[(long)b * H3 + c0 + j] = val + in.d_bhh[c0 + j];
      }
      gbar(w.flags1, epoch++, dead);
    }
    const float* ghb = w.gh_dbuf + (size_t)(t & 1) * BB * H3;
    for (int idx = tid; idx < BB * H; idx += NT) {
      int b = idx / H, k = idx - b * H;
      const float* gi = w.gi_d + ((long)(b * SS + t)) * H3;
      float ghr, ghz, ghn;
      if (t == 0) { ghr = in.d_bhh[k]; ghz = in.d_bhh[H + k]; ghn = in.d_bhh[2 * H + k]; }
      else { const float* gb = ghb + (long)b * H3; ghr = gb[k]; ghz = gb[H + k]; ghn = gb[2 * H + k]; }
      float r = sigm(gi[k] + ghr);
      float z = sigm(gi[H + k] + ghz);
      float n = tanhf(gi[2 * H + k] + r * ghn);
      float hprev = (t == 0) ? 0.f : hB[b][k];
      float hn = (1.f - z) * n + z * hprev;
      hB[b][k] = hn;
      if (wg == 0) w.dialogue[((long)(b * SS + t)) * H + k] = hn;
    }
    __syncthreads();
  }
}

__global__ __launch_bounds__(NT) void coop_main(IN in, WS w) {
  extern __shared__ char Lds[];
  u16*   wShh  = (u16*)(Lds + 0);        // [18][1536]
  u16*   wGab  = (u16*)(Lds + 55296);    // [9][1536]
  u16*   wMs   = (u16*)(Lds + 82944);    // [18][768]
  u16*   wMg   = (u16*)(Lds + 110592);   // [9][768]
  u16*   wGhh  = (u16*)(Lds + 124416);   // [9][768]
  float* OPMSl = (float*)(Lds + 138240); // [128][19] (padded)
  float* OPMGl = (float*)(Lds + 147968); // [128][9]
  float* h_lds = (float*)(Lds + 152576); // [1536]
  float* op_lds= (float*)(Lds + 158720); // [768]
  float* sc_l  = (float*)(Lds + 161792); // [128]
  float* pr_l  = (float*)(Lds + 162304); // [128]
  float* red   = (float*)(Lds + 162816); // [64]

  int tid = threadIdx.x, wg = blockIdx.x;
  int l = tid & 63, wv = tid >> 6;
  int c0sh = wg * 18, c0ab = wg * 9, c0ms = wg * 18, c0mg = wg * 9, c0gh = wg * 9;

  // ---- one-time LDS weight fill (reads original row-major f32 directly) ----
  for (int i = tid; i < 18 * H2; i += NT) wShh[i] = f2bf(in.s_whh[(long)(c0sh + i / H2) * H2 + (i % H2)]);
  for (int i = tid; i < 9 * H2;  i += NT) wGab[i] = f2bf(in.g_wih[(long)(c0ab + i / H2) * H3 + (i % H2)]);
  for (int i = tid; i < 18 * H;  i += NT) wMs[i]  = f2bf(w.Ms[(long)(c0ms + i / H) * H + (i % H)]);
  for (int i = tid; i < 9 * H;   i += NT) wMg[i]  = f2bf(w.Mg[(long)(c0mg + i / H) * H + (i % H)]);
  for (int i = tid; i < 9 * H;   i += NT) wGhh[i] = f2bf(in.g_whh[(long)(c0gh + i / H) * H + (i % H)]);
  for (int i = tid; i < H; i += NT) op_lds[i] = in.d_h0[i];
  __syncthreads();

  int epoch = 1, dead = 0;

  for (int g = 0; g <= GG; g++) {
    int s = g & 127, b = g >> 7;
    // ---- redundant op gates for step g-1 ----
    if (g > 0) {
      int po = (g - 1) & 1;
      const float* GIGr = w.GIG + (long)(g - 1) * H3;
      const float* giw = w.gig_w2 + po * H3;
      const float* ghg = w.gh_g2 + po * H3;
      for (int i = tid; i < H; i += NT) {
        float r = sigm(GIGr[i] + giw[i] + w.gig_h[i] + ghg[i]);
        float z = sigm(GIGr[H + i] + giw[H + i] + w.gig_h[H + i] + ghg[H + i]);
        float n = tanhf(GIGr[2 * H + i] + giw[2 * H + i] + w.gig_h[2 * H + i] + r * ghg[2 * H + i]);
        float opn = (1.f - z) * n + z * op_lds[i];
        op_lds[i] = opn;  // same-thread rewrite
        if (wg == 0) {
          w.out_op[(long)(g - 1) * H + i] = opn;
          w.op_buf[(long)((g - 1) & 127) * H + i] = opn;
        }
      }
      __syncthreads();
    }
    if (g == GG) break;

    int spk_cur = in.speaker_info[in.chat_ids[b] * SS + s];
    // preload speaker old-state into h_lds (race-free: written last before prev barrier)
    if (s == 0) {
      for (int i = tid; i < H2; i += NT) h_lds[i] = in.h0[i];
    } else {
      const float* sp = w.sp_global + (long)spk_cur * H2;
      for (int i = tid; i < H2; i += NT) h_lds[i] = sp[i];
    }

    // ---- redundant score(row s-1) + softmax ----
    if (s >= 1) {
      for (int j = tid; j <= s - 2; j += NT) sc_l[j] = w.scores_buf[j];
      const float* Ug = w.U + (long)g * H;
      float part = 0.f;
      for (int i = tid; i < H; i += NT) part = fmaf(op_lds[i], Ug[i], part);
      #pragma unroll
      for (int o = 32; o > 0; o >>= 1) part += __shfl_down(part, o);
      if (l == 0) red[32 + wv] = part;
      __syncthreads();
      if (tid == 0) {
        sc_l[s - 1] = red[32] + red[33] + red[34] + red[35] + w.cvec[g];
        sc_l[s] = w.cvec[g];  // still-zero op row contributes bk·q only
      }
      __syncthreads();
      float v = (tid <= s) ? sc_l[tid] : -3.0e38f;
      float m = v;
      #pragma unroll
      for (int o = 32; o > 0; o >>= 1) m = fmaxf(m, __shfl_xor(m, o));
      if (l == 0) red[36 + wv] = m;
      __syncthreads();
      m = fmaxf(fmaxf(red[36], red[37]), fmaxf(red[38], red[39]));
      float e = (tid <= s) ? expf(v - m) : 0.f;
      float su = e;
      #pragma unroll
      for (int o = 32; o > 0; o >>= 1) su += __shfl_xor(su, o);
      if (l == 0) red[40 + wv] = su;
      __syncthreads();
      su = red[40] + red[41] + red[42] + red[43];
      if (tid < SS) pr_l[tid] = (tid <= s - 1) ? e / su : 0.f;
      __syncthreads();
      if (wg == 0 && tid < SS) w.probs_buf[(long)g * SS + tid] = pr_l[tid];
    } else {
      if (tid < SS) pr_l[tid] = 0.f;
      __syncthreads();
      if (wg == 0 && tid < SS) w.probs_buf[(long)g * SS + tid] = 0.f;
    }

    // ---- PH1 distributed (per-WG column slices, LDS weights) ----
    int pn = g & 1;
    if (s == 0) {
      if (tid < 18) w.gi_attn[c0ms + tid] = w.ch0s[c0ms + tid];
      if (tid >= 32 && tid < 41) w.gig_w2[pn * H3 + c0mg + (tid - 32)] = w.chg0[c0mg + (tid - 32)];
      if (tid < 48) { int idx = wg * 48 + tid; w.sp_global[idx] = in.h0[idx % H2]; }  // batch reset
      if (wv == 3) {
        for (int j = 0; j < 9; j++) {
          float val = dot_bf<H>(wGhh + j * H, op_lds);
          if (l == 0) w.gh_g2[pn * H3 + c0gh + j] = val + in.g_bhh[c0gh + j];
        }
      }
    } else {
      // stage 1: new OPMS/OPMG row dots + gh_g
      if (wv < 2) {
        int j0 = wv * 9;
        for (int j = 0; j < 9; j++) {
          float val = dot_bf<H>(wMs + (j0 + j) * H, op_lds);
          if (l == 0) red[j0 + j] = val;
        }
      } else if (wv == 2) {
        for (int j = 0; j < 9; j++) {
          float val = dot_bf<H>(wMg + j * H, op_lds);
          if (l == 0) red[18 + j] = val;
        }
      } else {
        for (int j = 0; j < 9; j++) {
          float val = dot_bf<H>(wGhh + j * H, op_lds);
          if (l == 0) w.gh_g2[pn * H3 + c0gh + j] = val + in.g_bhh[c0gh + j];
        }
      }
      __syncthreads();
      // stage 2: probability-weighted sums over rows 0..s-2 (LDS) + emit
      float ps1 = pr_l[s - 1];
      if (wv < 2) {
        int j0 = wv * 9;
        for (int j = 0; j < 9; j++) {
          int c = j0 + j;
          float a = 0.f;
          if (l <= s - 2) a = pr_l[l] * OPMSl[l * 19 + c];
          if (l + 64 <= s - 2) a = fmaf(pr_l[l + 64], OPMSl[(l + 64) * 19 + c], a);
          #pragma unroll
          for (int o = 32; o > 0; o >>= 1) a += __shfl_down(a, o);
          if (l == 0) {
            float nr = red[c];
            OPMSl[(s - 1) * 19 + c] = nr;
            w.gi_attn[c0ms + c] = a + ps1 * nr + w.cvs[c0ms + c];
          }
        }
      } else if (wv == 2) {
        for (int j = 0; j < 9; j++) {
          float a = 0.f;
          if (l <= s - 2) a = pr_l[l] * OPMGl[l * 9 + j];
          if (l + 64 <= s - 2) a = fmaf(pr_l[l + 64], OPMGl[(l + 64) * 9 + j], a);
          #pragma unroll
          for (int o = 32; o > 0; o >>= 1) a += __shfl_down(a, o);
          if (l == 0) {
            float nr = red[18 + j];
            OPMGl[(s - 1) * 9 + j] = nr;
            w.gig_w2[pn * H3 + c0mg + j] = a + ps1 * nr + w.cvg[c0mg + j];
          }
        }
      }
    }
    gbar(w.flags2, epoch++, dead);

    // ---- PH2: redundant s-GRU gates ----
    {
      const float* GISr = w.GIS + (long)g * H6;
      const float* ghs = (s == 0) ? w.ghs0 : (w.gh_s2 + (size_t)(g & 1) * H6);
      for (int i = tid; i < H2; i += NT) {
        float spold = h_lds[i];
        float r = sigm(GISr[i] + w.gi_attn[i] + ghs[i]);
        float z = sigm(GISr[H2 + i] + w.gi_attn[H2 + i] + ghs[H2 + i]);
        float n = tanhf(GISr[2 * H2 + i] + w.gi_attn[2 * H2 + i] + r * ghs[2 * H2 + i]);
        float hn = (1.f - z) * n + z * spold;
        h_lds[i] = hn;
        if (wg == 0) {
          w.h_buf[(long)g * H2 + i] = hn;
          w.sp_global[(long)spk_cur * H2 + i] = hn;  // single writer; readers use h_lds if same spk
        }
      }
      __syncthreads();
    }
    // ---- PH2 distributed ----
    {
      int g1 = g + 1;
      int s1 = g1 & 127;
      // gig_h always (op gates at g+1 need it, incl. final g1==GG)
      if (wv == 2) {
        for (int j = 0; j < 9; j++) {
          float val = dot_bf<H2>(wGab + j * H2, h_lds);
          if (l == 0) w.gig_h[c0ab + j] = val;
        }
      }
      if (g1 < GG) {
        int b1 = g1 & 1;
        if (s1 == 0) {
          if (tid < 18) w.gh_s2[(size_t)b1 * H6 + c0sh + tid] = w.ghs0[c0sh + tid];
        } else if (wv < 2) {
          int spk_next = in.speaker_info[in.chat_ids[g1 >> 7] * SS + s1];
          const float* xn = (spk_next == spk_cur) ? h_lds : (w.sp_global + (long)spk_next * H2);
          int j0 = wv * 9;
          for (int j = 0; j < 9; j++) {
            float val = dot_bf<H2>(wShh + (j0 + j) * H2, xn);
            if (l == 0) w.gh_s2[(size_t)b1 * H6 + c0sh + j0 + j] = val + in.s_bhh[c0sh + j0 + j];
          }
        }
        if (wv == 3 && s1 >= 2 && wg < s1 - 1) {  // score row wg for next step
          const float* opr = w.op_buf + (long)wg * H;
          const float* Ur = w.U + (long)g1 * H;
          float a = 0.f;
          #pragma unroll
          for (int i0 = 0; i0 < 6; i0++) {
            int i = i0 * 64 + l;
            float2 xa = *(const float2*)(opr + 2 * i);
            float2 xb = *(const float2*)(Ur + 2 * i);
            a = fmaf(xa.x, xb.x, fmaf(xa.y, xb.y, a));
          }
          #pragma unroll
          for (int o = 32; o > 0; o >>= 1) a += __shfl_down(a, o);
          if (l == 0) w.scores_buf[wg] = a + w.cvec[g1];
        }
      }
    }
    gbar(w.flags2, epoch++, dead);
  }
}

// ================= epilogue =================

__global__ __launch_bounds__(NT) void fixup_u_k(WS w) {
  long i = (long)blockIdx.x * NT + threadIdx.x;
  if (i < (long)GG * H) {
    int m = (int)(i % H);
    w.U[i] = (w.U[i] + w.cu[m]) * INVSCALE;
  }
}

__global__ __launch_bounds__(NT) void cvec_k(WS w) {
  int g = blockIdx.x * 4 + (threadIdx.x >> 6);
  int l = threadIdx.x & 63;
  const float* d = w.dialogue + (long)g * H;
  float p = 0.f;
  for (int i = l; i < H; i += 64) p = fmaf(d[i], w.vkq[i], p);
  #pragma unroll
  for (int o = 32; o > 0; o >>= 1) p += __shfl_down(p, o);
  if (l == 0) w.cvec[g] = (p + w.cb[0]) * INVSCALE;
}

__global__ __launch_bounds__(NT) void epi_W_k(WS w) {
  int g = blockIdx.x, b = g >> 7;
  __shared__ float pl[SS];
  if (threadIdx.x < SS) pl[threadIdx.x] = w.probs_buf[(long)g * SS + threadIdx.x];
  __syncthreads();
  const float* opb = w.out_op + (long)b * SS * H;
  for (int n = threadIdx.x; n < H; n += NT) {
    float acc = 0.f;
    for (int j = 0; j < SS; j++) acc = fmaf(pl[j], opb[(long)j * H + n], acc);
    w.Wbuf[(long)g * H + n] = acc;
  }
}

__global__ __launch_bounds__(NT) void assemble_k(IN in, WS w) {
  long idx = (long)blockIdx.x * NT + threadIdx.x;
  if (idx >= (long)GG * H2) return;
  long g = idx / H2;
  int k = (int)(idx - g * H2);
  int s = (int)(g & 127);
  float t;
  if (k < H) t = (s == 0) ? in.attn_h[k] : w.AO[g * H + k];
  else t = w.dialogue[g * H + (k - H)];
  w.out_spop[idx] = w.h_buf[idx] + t;
}

// ================= host =================

extern "C" void kernel_launch(void* const* d_in, const int* in_sizes, int n_in,
                              void* d_out, int out_size, void* d_ws, size_t ws_size,
                              hipStream_t stream) {
  IN in;
  in.chat_ids = (const int*)d_in[0];
  in.speaker_info = (const int*)d_in[1];
  in.inputs = (const int*)d_in[4];
  in.emb = (const float*)d_in[5];
  in.d_wih = (const float*)d_in[6];  in.d_whh = (const float*)d_in[7];
  in.d_bih = (const float*)d_in[8];  in.d_bhh = (const float*)d_in[9];
  in.g_wih = (const float*)d_in[10]; in.g_whh = (const float*)d_in[11];
  in.g_bih = (const float*)d_in[12]; in.g_bhh = (const float*)d_in[13];
  in.s_wih = (const float*)d_in[14]; in.s_whh = (const float*)d_in[15];
  in.s_bih = (const float*)d_in[16]; in.s_bhh = (const float*)d_in[17];
  in.wq = (const float*)d_in[18];  in.bq = (const float*)d_in[19];
  in.wk = (const float*)d_in[20];  in.bk = (const float*)d_in[21];
  in.wv = (const float*)d_in[22];  in.bv = (const float*)d_in[23];
  in.h0 = (const float*)d_in[24];  in.d_h0 = (const float*)d_in[25];
  in.attn_h = (const float*)d_in[26];

  char* base = (char*)d_ws;
  size_t off = 0;
  auto A = [&](size_t bytes) -> void* {
    size_t r = (off + 255) & ~(size_t)255;
    off = r + bytes;
    return (void*)(base + r);
  };
  WS w;
  w.flags1 = (int*)A(NWG * 4);
  w.flags2 = (int*)A(NWG * 4);
  w.Mqk = (float*)A((size_t)H * H * 4);
  w.Gsum = (float*)A((size_t)H3 * H * 4);
  w.cu = (float*)A(H * 4);
  w.vkq = (float*)A(H * 4);
  w.cb = (float*)A(4);
  w.cvs = (float*)A(H6 * 4);
  w.ch0s = (float*)A(H6 * 4);
  w.cvg = (float*)A(H3 * 4);
  w.chg0 = (float*)A(H3 * 4);
  w.ghs0 = (float*)A(H6 * 4);
  w.Ms = (float*)A((size_t)H6 * H * 4);
  w.Mg = (float*)A((size_t)H3 * H * 4);
  {
    void* r1 = A((size_t)GG * H6 * 4);  // max(gi_d [GG*H3], GIS [GG*H6])
    w.gi_d = (float*)r1;
    w.GIS = (float*)r1;
  }
  w.dialogue = (float*)A((size_t)GG * H * 4);
  w.U = (float*)A((size_t)GG * H * 4);
  w.cvec = (float*)A(GG * 4);
  w.GIG = (float*)A((size_t)GG * H3 * 4);
  w.gh_dbuf = (float*)A((size_t)2 * BB * H3 * 4);
  w.sp_global = (float*)A((size_t)BB * H2 * 4);
  w.op_buf = (float*)A((size_t)SS * H * 4);
  w.gi_attn = (float*)A(H6 * 4);
  w.gh_s2 = (float*)A(2 * H6 * 4);
  w.gh_g2 = (float*)A(2 * H3 * 4);
  w.gig_w2 = (float*)A(2 * H3 * 4);
  w.gig_h = (float*)A(H3 * 4);
  w.scores_buf = (float*)A(SS * 4);
  w.probs_buf = (float*)A((size_t)GG * SS * 4);
  w.h_buf = (float*)A((size_t)GG * H2 * 4);
  w.Wbuf = (float*)A((size_t)GG * H * 4);
  w.AO = (float*)A((size_t)GG * H * 4);
  w.out_op = (float*)d_out;
  w.out_spop = (float*)d_out + (size_t)GG * H;

  hipFuncSetAttribute((const void*)coop_main, hipFuncAttributeMaxDynamicSharedMemorySize, DYN_LDS);

  hipMemsetAsync(w.flags1, 0, NWG * 4, stream);
  hipMemsetAsync(w.flags2, 0, NWG * 4, stream);

  const long NG = (long)H3 * H;
  prep1_k<<<(int)((NG + 2 * H + 1 + NT - 1) / NT), NT, 0, stream>>>(in, w);
  prep2_k<<<(H6 + H3 + H6 + NT - 1) / NT, NT, 0, stream>>>(in, w);

  // Mqk = wq^T @ wk
  gemm_k<<<dim3(H / 64, H / 64), NT, 0, stream>>>(in.wq, 1, H, nullptr, in.wk, H, 1, nullptr,
                                                  w.Mqk, H, H, H);
  // Ms = s_wihA @ wv  (row-major f32; LDS fill converts to bf16)
  gemm_k<<<dim3(H / 64, H6 / 64), NT, 0, stream>>>(in.s_wih, H2, 1, nullptr, in.wv, H, 1, nullptr,
                                                   w.Ms, H6, H, H);
  // Mg = g_wihA @ wv
  gemm_k<<<dim3(H / 64, H3 / 64), NT, 0, stream>>>(in.g_wih, H3, 1, nullptr, in.wv, H, 1, nullptr,
                                                   w.Mg, H3, H, H);
  // gi_d = emb[inputs] @ d_wih^T + d_bih
  gemm_k<<<dim3(H3 / 64, GG / 64), NT, 0, stream>>>(in.emb, H, 1, in.inputs, in.d_wih, 1, H,
                                                    in.d_bih, w.gi_d, GG, H3, H);
  coop_rnnD<<<NWG, NT, 0, stream>>>(in, w);

  // U = dialogue @ Mqk (then +cu, *1/scale)
  gemm_k<<<dim3(H / 64, GG / 64), NT, 0, stream>>>(w.dialogue, H, 1, nullptr, w.Mqk, H, 1, nullptr,
                                                   w.U, GG, H, H);
  // GIS = dialogue @ s_wihB^T + s_bih
  gemm_k<<<dim3(H6 / 64, GG / 64), NT, 0, stream>>>(w.dialogue, H, 1, nullptr, in.s_wih + H, 1, H2,
                                                    in.s_bih, w.GIS, GG, H6, H);
  // GIG = dialogue @ Gsum^T + g_bih
  gemm_k<<<dim3(H3 / 64, GG / 64), NT, 0, stream>>>(w.dialogue, H, 1, nullptr, w.Gsum, 1, H,
                                                    in.g_bih, w.GIG, GG, H3, H);
  fixup_u_k<<<(GG * H + NT - 1) / NT, NT, 0, stream>>>(w);
  cvec_k<<<GG / 4, NT, 0, stream>>>(w);

  coop_main<<<NWG, NT, DYN_LDS, stream>>>(in, w);

  epi_W_k<<<GG, NT, 0, stream>>>(w);
  // AO = Wbuf @ wv^T + bv
  gemm_k<<<dim3(H / 64, GG / 64), NT, 0, stream>>>(w.Wbuf, H, 1, nullptr, in.wv, 1, H,
                                                   in.bv, w.AO, GG, H, H);
  assemble_k<<<(int)(((long)GG * H2 + NT - 1) / NT), NT, 0, stream>>>(in, w);
}

// Round 4
// 25675.232 us; speedup vs baseline: 4.2862x; 4.2862x over previous
//
#include <hip/hip_runtime.h>
#include <hip/hip_bf16.h>

typedef unsigned int uint32;
typedef unsigned short u16;
typedef unsigned long long u64;
typedef __attribute__((ext_vector_type(8))) short s16x8;
typedef __attribute__((ext_vector_type(4))) float f32x4;

#define H    768
#define H2   1536
#define H3   2304
#define H6   4608
#define BB   8
#define SS   128
#define GG   1024
#define NWG  256
#define NT   256
#define INVSCALE 0.036084391824351615f
#define SPIN_LIMIT (1 << 16)
#define DYN_LDS 162816

struct IN {
  const int *chat_ids, *speaker_info, *inputs;
  const float *emb, *d_wih, *d_whh, *d_bih, *d_bhh;
  const float *g_wih, *g_whh, *g_bih, *g_bhh;
  const float *s_wih, *s_whh, *s_bih, *s_bhh;
  const float *wq, *bq, *wk, *bk, *wv, *bv;
  const float *h0, *d_h0, *attn_h;
};

struct WS {
  int *flags1, *go1, *flags2, *go2;
  float *Mqk, *Gsum;
  float *cu, *vkq, *cb, *cvs, *ch0s, *cvg, *chg0, *ghs0;
  float *Ms, *Mg;
  float *gi_d, *GIS;           // aliased region
  float *dialogue, *U, *cvec, *GIG;
  float *gh_dbuf;              // [2][BB][H3]
  float *sp_global;            // [8][H2]
  float *op_buf;               // [SS][H]
  float *comb_gi, *comb_gh;    // [H3] input-side / hidden-side for g-GRU
  float *comb_si, *comb_sh;    // [H6] input-side / hidden-side for s-GRU
  float *scores_buf, *probs_buf;
  float *h_buf, *Wbuf, *AO;
  float *out_op, *out_spop;
};

__device__ inline float sigm(float x) { return 1.f / (1.f + expf(-x)); }

__device__ inline u16 f2bf(float v) {
  __hip_bfloat16 b = __float2bfloat16(v);
  return *reinterpret_cast<u16*>(&b);
}
__device__ inline uint32 pack2bf(float a, float b) {
  return (uint32)f2bf(a) | ((uint32)f2bf(b) << 16);
}

// ---- agent-scope write-through accessors (bypass non-coherent per-XCD L2) ----
__device__ inline float2 ld2(const float* p) { return *(const float2*)p; }
__device__ inline float2 ald2(const float* p) {
  u64 v = __hip_atomic_load((const u64*)p, __ATOMIC_RELAXED, __HIP_MEMORY_SCOPE_AGENT);
  union { u64 u; float2 f; } c; c.u = v; return c.f;
}
__device__ inline void ast2(float* p, float2 f) {
  union { u64 u; float2 f; } c; c.f = f;
  __hip_atomic_store((u64*)p, c.u, __ATOMIC_RELAXED, __HIP_MEMORY_SCOPE_AGENT);
}
__device__ inline float ald(const float* p) {
  return __hip_atomic_load(p, __ATOMIC_RELAXED, __HIP_MEMORY_SCOPE_AGENT);
}
__device__ inline void ast(float* p, float v) {
  __hip_atomic_store(p, v, __ATOMIC_RELAXED, __HIP_MEMORY_SCOPE_AGENT);
}

// ---- fence-free hierarchical grid barrier ----
__device__ inline void gbar(int* flags, int* go, int epoch, int& dead) {
  int bail = 0;
  __syncthreads();
  if (!dead) {
    if (blockIdx.x == 0) {
      if (threadIdx.x > 0 && threadIdx.x < NWG) {
        int spins = 0;
        while (__hip_atomic_load(&flags[threadIdx.x * 16], __ATOMIC_RELAXED, __HIP_MEMORY_SCOPE_AGENT) < epoch) {
          __builtin_amdgcn_s_sleep(2);
          if (++spins > SPIN_LIMIT) { bail = 1; break; }
        }
      }
    } else if (threadIdx.x == 0) {
      __hip_atomic_store(&flags[blockIdx.x * 16], epoch, __ATOMIC_RELAXED, __HIP_MEMORY_SCOPE_AGENT);
    }
  }
  dead |= __syncthreads_or(bail);
  bail = 0;
  if (!dead) {
    if (blockIdx.x == 0) {
      if (threadIdx.x == 0)
        __hip_atomic_store(go, epoch, __ATOMIC_RELAXED, __HIP_MEMORY_SCOPE_AGENT);
    } else if (threadIdx.x == 0) {
      int spins = 0;
      while (__hip_atomic_load(go, __ATOMIC_RELAXED, __HIP_MEMORY_SCOPE_AGENT) < epoch) {
        __builtin_amdgcn_s_sleep(2);
        if (++spins > SPIN_LIMIT) { bail = 1; break; }
      }
    }
  }
  dead |= __syncthreads_or(bail);
  asm volatile("" ::: "memory");
}

// ---- register-x dot helpers ----
template <int NI>
__device__ inline float dotr(const u16* wcol, const float2* xr) {
  const uint32* wp = (const uint32*)wcol;
  int l = threadIdx.x & 63;
  float acc = 0.f;
  #pragma unroll
  for (int i = 0; i < NI; i++) {
    uint32 u = wp[i * 64 + l];
    acc = fmaf(xr[i].x, __uint_as_float(u << 16),
          fmaf(xr[i].y, __uint_as_float(u & 0xffff0000u), acc));
  }
  #pragma unroll
  for (int o = 32; o > 0; o >>= 1) acc += __shfl_down(acc, o);
  return acc;  // valid on lane 0
}
template <int NI>
__device__ inline void loadx_lds(float2* xr, const float* x) {
  int l = threadIdx.x & 63;
  #pragma unroll
  for (int i = 0; i < NI; i++) xr[i] = ld2(x + 2 * (i * 64 + l));
}
template <int NI>
__device__ inline void loadx_atm(float2* xr, const float* x) {
  int l = threadIdx.x & 63;
  #pragma unroll
  for (int i = 0; i < NI; i++) xr[i] = ald2(x + 2 * (i * 64 + l));
}

// ================= prep kernels =================

__global__ __launch_bounds__(NT) void prep1_k(IN in, WS w) {
  long i = (long)blockIdx.x * NT + threadIdx.x;
  const long NG = (long)H3 * H;
  if (i < NG) {
    long n = i / H, k = i - n * H;
    w.Gsum[i] = in.g_wih[n * H3 + H + k] + in.g_wih[n * H3 + 2 * H + k];
  } else if (i < NG + H) {
    int m = (int)(i - NG);
    float a = 0.f;
    for (int t = 0; t < H; t++) a = fmaf(in.bq[t], in.wk[(long)t * H + m], a);
    w.cu[m] = a;
  } else if (i < NG + 2 * H) {
    int m = (int)(i - NG - H);
    float a = 0.f;
    for (int t = 0; t < H; t++) a = fmaf(in.bk[t], in.wq[(long)t * H + m], a);
    w.vkq[m] = a;
  } else if (i == NG + 2 * H) {
    float a = 0.f;
    for (int t = 0; t < H; t++) a = fmaf(in.bk[t], in.bq[t], a);
    w.cb[0] = a;
  }
}

__global__ __launch_bounds__(NT) void prep2_k(IN in, WS w) {
  int wid = blockIdx.x * (NT / 64) + (threadIdx.x >> 6);
  int l = threadIdx.x & 63;
  const int R1 = H6, R2 = H6 + H3, R3 = H6 + H3 + H6;
  if (wid < R1) {
    const float* row = in.s_wih + (long)wid * H2;
    float a = 0.f, c = 0.f;
    for (int i = l; i < H; i += 64) { float rv = row[i]; a = fmaf(in.bv[i], rv, a); c = fmaf(in.attn_h[i], rv, c); }
    #pragma unroll
    for (int o = 32; o > 0; o >>= 1) { a += __shfl_down(a, o); c += __shfl_down(c, o); }
    if (l == 0) { w.cvs[wid] = a; w.ch0s[wid] = c; }
  } else if (wid < R2) {
    int k = wid - R1;
    const float* row = in.g_wih + (long)k * H3;
    float a = 0.f, c = 0.f;
    for (int i = l; i < H; i += 64) { float rv = row[i]; a = fmaf(in.bv[i], rv, a); c = fmaf(in.attn_h[i], rv, c); }
    #pragma unroll
    for (int o = 32; o > 0; o >>= 1) { a += __shfl_down(a, o); c += __shfl_down(c, o); }
    if (l == 0) { w.cvg[k] = a; w.chg0[k] = c; }
  } else if (wid < R3) {
    int k = wid - R2;
    const float* row = in.s_whh + (long)k * H2;
    float a = 0.f;
    for (int i = l; i < H2; i += 64) a = fmaf(in.h0[i], row[i], a);
    #pragma unroll
    for (int o = 32; o > 0; o >>= 1) a += __shfl_down(a, o);
    if (l == 0) w.ghs0[k] = a + in.s_bhh[k];
  }
}

// ---- f32 GEMM (kept only for Mqk: col-major A) ----
__global__ __launch_bounds__(NT) void gemm_k(const float* A, long sAm, long sAk,
                                             const float* B, long sBk,
                                             float* C, int M, int N, int K) {
  __shared__ float As[16][65];
  __shared__ float Bs[16][65];
  int m0 = blockIdx.y * 64, n0 = blockIdx.x * 64;
  int tid = threadIdx.x;
  int tx = tid & 15, ty = tid >> 4;
  float acc[4][4] = {};
  for (int k0 = 0; k0 < K; k0 += 16) {
    {
      int m = tid & 63, kb = tid >> 6;
      for (int p = 0; p < 4; p++) {
        int k = kb + p * 4;
        As[k][m] = A[(long)(m0 + m) * sAm + (long)(k0 + k) * sAk];
      }
    }
    {
      int n = tid & 63, kb = tid >> 6;
      for (int p = 0; p < 4; p++) {
        int k = kb + p * 4;
        Bs[k][n] = B[(long)(k0 + k) * sBk + (n0 + n)];
      }
    }
    __syncthreads();
    #pragma unroll
    for (int k = 0; k < 16; k++) {
      float a[4], b[4];
      #pragma unroll
      for (int i = 0; i < 4; i++) a[i] = As[k][ty * 4 + i];
      #pragma unroll
      for (int j = 0; j < 4; j++) b[j] = Bs[k][tx * 4 + j];
      #pragma unroll
      for (int i = 0; i < 4; i++)
        #pragma unroll
        for (int j = 0; j < 4; j++) acc[i][j] = fmaf(a[i], b[j], acc[i][j]);
    }
    __syncthreads();
  }
  for (int i = 0; i < 4; i++)
    for (int j = 0; j < 4; j++) {
      int m = m0 + ty * 4 + i, n = n0 + tx * 4 + j;
      C[(long)m * N + n] = acc[i][j];
    }
}

// ---- MFMA bf16 GEMM ----
__global__ __launch_bounds__(NT) void mgemm_k(const float* A, long sAm, const int* gather,
                                              const float* B, long sB, int bColMajor,
                                              const float* bias, float* C, int N, int K) {
  __shared__ u16 Al[128 * 40];
  __shared__ u16 Bl[128 * 40];
  int tid = threadIdx.x;
  int n0 = blockIdx.x * 128, m0 = blockIdx.y * 128;
  int l = tid & 63, wv = tid >> 6;
  int wr = wv >> 1, wc = wv & 1;
  f32x4 acc[4][4] = {};
  long arow = gather ? (long)gather[m0 + (tid >> 1)] : (long)(m0 + (tid >> 1));
  for (int k0 = 0; k0 < K; k0 += 32) {
    __syncthreads();
    {
      int r = tid >> 1, half = tid & 1;
      const float* src = A + arow * sAm + k0 + half * 16;
      uint32* dst = (uint32*)(Al + r * 40 + half * 16);
      #pragma unroll
      for (int j = 0; j < 8; j++) dst[j] = pack2bf(src[2 * j], src[2 * j + 1]);
    }
    if (bColMajor) {
      int n = tid >> 1, half = tid & 1;
      const float* src = B + (long)(n0 + n) * sB + k0 + half * 16;
      uint32* dst = (uint32*)(Bl + n * 40 + half * 16);
      #pragma unroll
      for (int j = 0; j < 8; j++) dst[j] = pack2bf(src[2 * j], src[2 * j + 1]);
    } else {
      int kk = tid & 31, nb = tid >> 5;
      const float* src = B + (long)(k0 + kk) * sB + n0 + nb * 16;
      #pragma unroll
      for (int j = 0; j < 16; j++) Bl[(nb * 16 + j) * 40 + kk] = f2bf(src[j]);
    }
    __syncthreads();
    s16x8 af[4], bf[4];
    #pragma unroll
    for (int i = 0; i < 4; i++) {
      af[i] = *(const s16x8*)(Al + (wr * 64 + i * 16 + (l & 15)) * 40 + (l >> 4) * 8);
      bf[i] = *(const s16x8*)(Bl + (wc * 64 + i * 16 + (l & 15)) * 40 + (l >> 4) * 8);
    }
    #pragma unroll
    for (int i = 0; i < 4; i++)
      #pragma unroll
      for (int j = 0; j < 4; j++)
        acc[i][j] = __builtin_amdgcn_mfma_f32_16x16x32_bf16(af[i], bf[j], acc[i][j], 0, 0, 0);
  }
  #pragma unroll
  for (int i = 0; i < 4; i++)
    #pragma unroll
    for (int j = 0; j < 4; j++) {
      int n = n0 + wc * 64 + j * 16 + (l & 15);
      int mb = m0 + wr * 64 + i * 16 + ((l >> 4) << 2);
      float bb = bias ? bias[n] : 0.f;
      #pragma unroll
      for (int r = 0; r < 4; r++)
        C[(long)(mb + r) * N + n] = acc[i][j][r] + bb;
    }
}

// ================= sequential kernels =================

__global__ __launch_bounds__(NT) void coop_rnnD(IN in, WS w) {
  __shared__ u16 wD[9 * H];
  __shared__ float hB[BB][H];
  int tid = threadIdx.x, wg = blockIdx.x;
  int c0 = wg * 9;
  int l = tid & 63, wv = tid >> 6;
  for (int i = tid; i < 9 * H; i += NT)
    wD[i] = f2bf(in.d_whh[(long)(c0 + i / H) * H + (i % H)]);
  for (int i = tid; i < BB * H; i += NT) ((float*)hB)[i] = 0.f;
  __syncthreads();
  int epoch = 1, dead = 0;
  for (int t = 0; t < SS; t++) {
    if (t > 0) {
      float* ghb = w.gh_dbuf + (size_t)(t & 1) * BB * H3;
      for (int bi = 0; bi < 2; bi++) {
        int b = wv * 2 + bi;
        float2 xr[6];
        loadx_lds<6>(xr, hB[b]);
        for (int j = 0; j < 9; j++) {
          float val = dotr<6>(wD + j * H, xr);
          if (l == 0) ast(ghb + (long)b * H3 + c0 + j, val + in.d_bhh[c0 + j]);
        }
      }
      gbar(w.flags1, w.go1, epoch++, dead);
    }
    const float* ghb = w.gh_dbuf + (size_t)(t & 1) * BB * H3;
    for (int pc = tid; pc < BB * H / 2; pc += NT) {
      int b = pc / (H / 2), k = 2 * (pc - b * (H / 2));
      const float* gi = w.gi_d + ((long)(b * SS + t)) * H3;
      float2 gr = ld2(gi + k), gz = ld2(gi + H + k), gn = ld2(gi + 2 * H + k);
      float2 hr, hz, hn2;
      if (t == 0) {
        hr = ld2(in.d_bhh + k); hz = ld2(in.d_bhh + H + k); hn2 = ld2(in.d_bhh + 2 * H + k);
      } else {
        const float* gb = ghb + (long)b * H3;
        hr = ald2(gb + k); hz = ald2(gb + H + k); hn2 = ald2(gb + 2 * H + k);
      }
      float p0 = (t == 0) ? 0.f : hB[b][k], p1 = (t == 0) ? 0.f : hB[b][k + 1];
      float r0 = sigm(gr.x + hr.x), r1 = sigm(gr.y + hr.y);
      float z0 = sigm(gz.x + hz.x), z1 = sigm(gz.y + hz.y);
      float n0 = tanhf(gn.x + r0 * hn2.x), n1 = tanhf(gn.y + r1 * hn2.y);
      float h0v = (1.f - z0) * n0 + z0 * p0, h1v = (1.f - z1) * n1 + z1 * p1;
      hB[b][k] = h0v; hB[b][k + 1] = h1v;
      if (wg == 0) *(float2*)(w.dialogue + ((long)(b * SS + t)) * H + k) = make_float2(h0v, h1v);
    }
    __syncthreads();
  }
}

__global__ __launch_bounds__(NT) void coop_main(IN in, WS w) {
  extern __shared__ char Lds[];
  u16*   wShh  = (u16*)(Lds + 0);        // [18][1536]
  u16*   wGab  = (u16*)(Lds + 55296);    // [9][1536]
  u16*   wMs   = (u16*)(Lds + 82944);    // [18][768]
  u16*   wMg   = (u16*)(Lds + 110592);   // [9][768]
  u16*   wGhh  = (u16*)(Lds + 124416);   // [9][768]
  float* OPMSl = (float*)(Lds + 138240); // [128][18]
  float* OPMGl = (float*)(Lds + 147456); // [128][9]
  float* h_lds = (float*)(Lds + 152064); // [1536]
  float* op_lds= (float*)(Lds + 158208); // [768]
  float* sc_l  = (float*)(Lds + 161280); // [128]
  float* pr_l  = (float*)(Lds + 161792); // [128]
  float* red   = (float*)(Lds + 162304); // [32]
  float* stash = (float*)(Lds + 162432); // gw[9], gg[9], ghs[18]
  float* stash_gw = stash, *stash_gg = stash + 9, *stash_ghs = stash + 18;

  int tid = threadIdx.x, wg = blockIdx.x;
  int l = tid & 63, wv = tid >> 6;
  int c0sh = wg * 18;   // s-domain columns
  int c0g  = wg * 9;    // g-domain columns

  for (int i = tid; i < 18 * H2; i += NT) wShh[i] = f2bf(in.s_whh[(long)(c0sh + i / H2) * H2 + (i % H2)]);
  for (int i = tid; i < 9 * H2;  i += NT) wGab[i] = f2bf(in.g_wih[(long)(c0g + i / H2) * H3 + (i % H2)]);
  for (int i = tid; i < 18 * H;  i += NT) wMs[i]  = f2bf(w.Ms[(long)(c0sh + i / H) * H + (i % H)]);
  for (int i = tid; i < 9 * H;   i += NT) wMg[i]  = f2bf(w.Mg[(long)(c0g + i / H) * H + (i % H)]);
  for (int i = tid; i < 9 * H;   i += NT) wGhh[i] = f2bf(in.g_whh[(long)(c0g + i / H) * H + (i % H)]);
  for (int i = tid; i < H; i += NT) op_lds[i] = in.d_h0[i];
  __syncthreads();

  int epoch = 1, dead = 0;
  int spk_prev = -1;

  for (int g = 0; g <= GG; g++) {
    int s = g & 127, b = g >> 7;
    // ---- OP-GATES for step g-1 (input/hidden streams kept separate for n-gate) ----
    if (g > 0) {
      const float* GIGr = w.GIG + (long)(g - 1) * H3;
      for (int pc = tid; pc < H / 2; pc += NT) {
        int i = 2 * pc;
        float2 gr = ld2(GIGr + i), gz = ld2(GIGr + H + i), gn = ld2(GIGr + 2 * H + i);
        float2 ir = ald2(w.comb_gi + i), iz = ald2(w.comb_gi + H + i), inn = ald2(w.comb_gi + 2 * H + i);
        float2 hr = ald2(w.comb_gh + i), hz = ald2(w.comb_gh + H + i), hn = ald2(w.comb_gh + 2 * H + i);
        float o0p = op_lds[i], o1p = op_lds[i + 1];
        float r0 = sigm(gr.x + ir.x + hr.x), r1 = sigm(gr.y + ir.y + hr.y);
        float z0 = sigm(gz.x + iz.x + hz.x), z1 = sigm(gz.y + iz.y + hz.y);
        float n0 = tanhf(gn.x + inn.x + r0 * hn.x), n1 = tanhf(gn.y + inn.y + r1 * hn.y);
        float o0 = (1.f - z0) * n0 + z0 * o0p, o1 = (1.f - z1) * n1 + z1 * o1p;
        op_lds[i] = o0; op_lds[i + 1] = o1;
        if (wg == 0) {
          *(float2*)(w.out_op + (long)(g - 1) * H + i) = make_float2(o0, o1);
          ast2(w.op_buf + (long)((g - 1) & 127) * H + i, make_float2(o0, o1));
        }
      }
      __syncthreads();
    }
    if (g == GG) break;

    int spk_cur = in.speaker_info[in.chat_ids[b] * SS + s];
    if (s == 0) {
      for (int i = tid; i < H2; i += NT) h_lds[i] = in.h0[i];
    } else if (spk_cur != spk_prev) {
      const float* sp = w.sp_global + (long)spk_cur * H2;
      for (int pc = tid; pc < H2 / 2; pc += NT) {
        float2 v = ald2(sp + 2 * pc);
        h_lds[2 * pc] = v.x; h_lds[2 * pc + 1] = v.y;
      }
    }

    // ---- softmax (redundant) ----
    if (s >= 1) {
      if (tid <= s - 2) sc_l[tid] = ald(w.scores_buf + tid);
      const float* Ug = w.U + (long)g * H;
      float part = 0.f;
      for (int pc = tid; pc < H / 2; pc += NT) {
        float2 u = ld2(Ug + 2 * pc);
        part = fmaf(op_lds[2 * pc], u.x, fmaf(op_lds[2 * pc + 1], u.y, part));
      }
      #pragma unroll
      for (int o = 32; o > 0; o >>= 1) part += __shfl_down(part, o);
      if (l == 0) red[wv] = part;
      __syncthreads();
      if (tid == 0) {
        float cv = w.cvec[g];
        sc_l[s - 1] = red[0] + red[1] + red[2] + red[3] + cv;
        sc_l[s] = cv;
      }
      __syncthreads();
      float v = (tid <= s) ? sc_l[tid] : -3.0e38f;
      float m = v;
      #pragma unroll
      for (int o = 32; o > 0; o >>= 1) m = fmaxf(m, __shfl_xor(m, o));
      if (l == 0) red[4 + wv] = m;
      __syncthreads();
      m = fmaxf(fmaxf(red[4], red[5]), fmaxf(red[6], red[7]));
      float e = (tid <= s) ? expf(v - m) : 0.f;
      float su = e;
      #pragma unroll
      for (int o = 32; o > 0; o >>= 1) su += __shfl_xor(su, o);
      if (l == 0) red[8 + wv] = su;
      __syncthreads();
      su = red[8] + red[9] + red[10] + red[11];
      if (tid < SS) pr_l[tid] = (tid <= s - 1) ? e / su : 0.f;
      __syncthreads();
      if (wg == 0 && tid < SS) w.probs_buf[(long)g * SS + tid] = pr_l[tid];
    } else {
      if (tid < SS) pr_l[tid] = 0.f;
      __syncthreads();
      if (wg == 0 && tid < SS) w.probs_buf[(long)g * SS + tid] = 0.f;
    }

    // ---- PH1 distributed ----
    if (s == 0) {
      if (tid < 18) {
        ast(w.comb_si + c0sh + tid, w.ch0s[c0sh + tid]);
        ast(w.comb_sh + c0sh + tid, w.ghs0[c0sh + tid]);
      }
      if (wv == 1 && l < 9) stash_gw[l] = w.chg0[c0g + l];
      if (wv == 3) {
        float2 xr[6];
        loadx_lds<6>(xr, op_lds);
        for (int j = 0; j < 9; j++) {
          float val = dotr<6>(wGhh + j * H, xr);
          if (l == 0) stash_gg[j] = val + in.g_bhh[c0g + j];
        }
      }
      if (tid < 48) { int idx = wg * 48 + tid; ast(w.sp_global + idx, in.h0[idx % H2]); }
    } else {
      float2 xr[6];
      loadx_lds<6>(xr, op_lds);
      if (wv < 2) {
        int j0 = wv * 9;
        for (int j = 0; j < 9; j++) {
          float val = dotr<6>(wMs + (j0 + j) * H, xr);
          if (l == 0) red[j0 + j] = val;
        }
      } else if (wv == 2) {
        for (int j = 0; j < 9; j++) {
          float val = dotr<6>(wMg + j * H, xr);
          if (l == 0) red[18 + j] = val;
        }
      } else {
        for (int j = 0; j < 9; j++) {
          float val = dotr<6>(wGhh + j * H, xr);
          if (l == 0) stash_gg[j] = val + in.g_bhh[c0g + j];
        }
      }
      __syncthreads();
      float ps1 = pr_l[s - 1];
      if (wv < 2) {
        int j0 = wv * 9;
        for (int j = 0; j < 9; j++) {
          int c = j0 + j;
          float a = 0.f;
          if (l <= s - 2) a = pr_l[l] * OPMSl[l * 18 + c];
          if (l + 64 <= s - 2) a = fmaf(pr_l[l + 64], OPMSl[(l + 64) * 18 + c], a);
          #pragma unroll
          for (int o = 32; o > 0; o >>= 1) a += __shfl_down(a, o);
          if (l == 0) {
            float nr = red[c];
            OPMSl[(s - 1) * 18 + c] = nr;
            ast(w.comb_si + c0sh + c, a + ps1 * nr + w.cvs[c0sh + c]);
            ast(w.comb_sh + c0sh + c, stash_ghs[c]);
          }
        }
      } else if (wv == 2) {
        for (int j = 0; j < 9; j++) {
          float a = 0.f;
          if (l <= s - 2) a = pr_l[l] * OPMGl[l * 9 + j];
          if (l + 64 <= s - 2) a = fmaf(pr_l[l + 64], OPMGl[(l + 64) * 9 + j], a);
          #pragma unroll
          for (int o = 32; o > 0; o >>= 1) a += __shfl_down(a, o);
          if (l == 0) {
            float nr = red[18 + j];
            OPMGl[(s - 1) * 9 + j] = nr;
            stash_gw[j] = a + ps1 * nr + w.cvg[c0g + j];
          }
        }
      }
    }
    gbar(w.flags2, w.go2, epoch++, dead);

    // ---- PH2: S-GATES (input/hidden separate for n-gate) ----
    {
      const float* GISr = w.GIS + (long)g * H6;
      for (int pc = tid; pc < H2 / 2; pc += NT) {
        int i = 2 * pc;
        float2 gr = ld2(GISr + i), gz = ld2(GISr + H2 + i), gn = ld2(GISr + 2 * H2 + i);
        float2 ir = ald2(w.comb_si + i), iz = ald2(w.comb_si + H2 + i), inn = ald2(w.comb_si + 2 * H2 + i);
        float2 hr = ald2(w.comb_sh + i), hz = ald2(w.comb_sh + H2 + i), hn = ald2(w.comb_sh + 2 * H2 + i);
        float s0 = h_lds[i], s1v = h_lds[i + 1];
        float r0 = sigm(gr.x + ir.x + hr.x), r1 = sigm(gr.y + ir.y + hr.y);
        float z0 = sigm(gz.x + iz.x + hz.x), z1 = sigm(gz.y + iz.y + hz.y);
        float n0 = tanhf(gn.x + inn.x + r0 * hn.x), n1 = tanhf(gn.y + inn.y + r1 * hn.y);
        float h0v = (1.f - z0) * n0 + z0 * s0, h1v = (1.f - z1) * n1 + z1 * s1v;
        h_lds[i] = h0v; h_lds[i + 1] = h1v;
        if (wg == 0) {
          *(float2*)(w.h_buf + (long)g * H2 + i) = make_float2(h0v, h1v);
          ast2(w.sp_global + (long)spk_cur * H2 + i, make_float2(h0v, h1v));
        }
      }
      __syncthreads();
    }
    // ---- PH2 distributed ----
    {
      int g1 = g + 1, s1 = g1 & 127;
      if (wv == 2) {
        float2 xr[12];
        loadx_lds<12>(xr, h_lds);
        for (int j = 0; j < 9; j++) {
          float val = dotr<12>(wGab + j * H2, xr);
          if (l == 0) {
            ast(w.comb_gi + c0g + j, stash_gw[j] + val);
            ast(w.comb_gh + c0g + j, stash_gg[j]);
          }
        }
      }
      if (g1 < GG) {
        if (s1 != 0 && wv < 2) {
          int spk_next = in.speaker_info[in.chat_ids[g1 >> 7] * SS + s1];
          float2 xr[12];
          if (spk_next == spk_cur) loadx_lds<12>(xr, h_lds);
          else loadx_atm<12>(xr, w.sp_global + (long)spk_next * H2);
          int j0 = wv * 9;
          for (int j = 0; j < 9; j++) {
            float val = dotr<12>(wShh + (j0 + j) * H2, xr);
            if (l == 0) stash_ghs[j0 + j] = val + in.s_bhh[c0sh + j0 + j];
          }
        }
        if (wv == 3 && s1 >= 2 && wg < s1 - 1) {
          const float* opr = w.op_buf + (long)wg * H;
          const float* Ur = w.U + (long)g1 * H;
          float a = 0.f;
          #pragma unroll
          for (int i0 = 0; i0 < 6; i0++) {
            int idx = i0 * 64 + l;
            float2 xa = ald2(opr + 2 * idx);
            float2 xb = ld2(Ur + 2 * idx);
            a = fmaf(xa.x, xb.x, fmaf(xa.y, xb.y, a));
          }
          #pragma unroll
          for (int o = 32; o > 0; o >>= 1) a += __shfl_down(a, o);
          if (l == 0) ast(w.scores_buf + wg, a + w.cvec[g1]);
        }
      }
    }
    gbar(w.flags2, w.go2, epoch++, dead);
    spk_prev = spk_cur;
  }
}

// ================= epilogue =================

__global__ __launch_bounds__(NT) void fixup_u_k(WS w) {
  long i = (long)blockIdx.x * NT + threadIdx.x;
  if (i < (long)GG * H) {
    int m = (int)(i % H);
    w.U[i] = (w.U[i] + w.cu[m]) * INVSCALE;
  }
}

__global__ __launch_bounds__(NT) void cvec_k(WS w) {
  int g = blockIdx.x * 4 + (threadIdx.x >> 6);
  int l = threadIdx.x & 63;
  const float* d = w.dialogue + (long)g * H;
  float p = 0.f;
  for (int i = l; i < H; i += 64) p = fmaf(d[i], w.vkq[i], p);
  #pragma unroll
  for (int o = 32; o > 0; o >>= 1) p += __shfl_down(p, o);
  if (l == 0) w.cvec[g] = (p + w.cb[0]) * INVSCALE;
}

__global__ __launch_bounds__(NT) void epi_W_k(WS w) {
  int g = blockIdx.x, b = g >> 7;
  __shared__ float pl[SS];
  if (threadIdx.x < SS) pl[threadIdx.x] = w.probs_buf[(long)g * SS + threadIdx.x];
  __syncthreads();
  const float* opb = w.out_op + (long)b * SS * H;
  for (int n = threadIdx.x; n < H; n += NT) {
    float acc = 0.f;
    for (int j = 0; j < SS; j++) acc = fmaf(pl[j], opb[(long)j * H + n], acc);
    w.Wbuf[(long)g * H + n] = acc;
  }
}

__global__ __launch_bounds__(NT) void assemble_k(IN in, WS w) {
  long idx = (long)blockIdx.x * NT + threadIdx.x;
  if (idx >= (long)GG * H2) return;
  long g = idx / H2;
  int k = (int)(idx - g * H2);
  int s = (int)(g & 127);
  float t;
  if (k < H) t = (s == 0) ? in.attn_h[k] : w.AO[g * H + k];
  else t = w.dialogue[g * H + (k - H)];
  w.out_spop[idx] = w.h_buf[idx] + t;
}

// ================= host =================

extern "C" void kernel_launch(void* const* d_in, const int* in_sizes, int n_in,
                              void* d_out, int out_size, void* d_ws, size_t ws_size,
                              hipStream_t stream) {
  IN in;
  in.chat_ids = (const int*)d_in[0];
  in.speaker_info = (const int*)d_in[1];
  in.inputs = (const int*)d_in[4];
  in.emb = (const float*)d_in[5];
  in.d_wih = (const float*)d_in[6];  in.d_whh = (const float*)d_in[7];
  in.d_bih = (const float*)d_in[8];  in.d_bhh = (const float*)d_in[9];
  in.g_wih = (const float*)d_in[10]; in.g_whh = (const float*)d_in[11];
  in.g_bih = (const float*)d_in[12]; in.g_bhh = (const float*)d_in[13];
  in.s_wih = (const float*)d_in[14]; in.s_whh = (const float*)d_in[15];
  in.s_bih = (const float*)d_in[16]; in.s_bhh = (const float*)d_in[17];
  in.wq = (const float*)d_in[18];  in.bq = (const float*)d_in[19];
  in.wk = (const float*)d_in[20];  in.bk = (const float*)d_in[21];
  in.wv = (const float*)d_in[22];  in.bv = (const float*)d_in[23];
  in.h0 = (const float*)d_in[24];  in.d_h0 = (const float*)d_in[25];
  in.attn_h = (const float*)d_in[26];

  char* base = (char*)d_ws;
  size_t off = 0;
  auto A = [&](size_t bytes) -> void* {
    size_t r = (off + 255) & ~(size_t)255;
    off = r + bytes;
    return (void*)(base + r);
  };
  WS w;
  w.flags1 = (int*)A(NWG * 16 * 4);
  w.go1 = (int*)A(64);
  w.flags2 = (int*)A(NWG * 16 * 4);
  w.go2 = (int*)A(64);
  w.Mqk = (float*)A((size_t)H * H * 4);
  w.Gsum = (float*)A((size_t)H3 * H * 4);
  w.cu = (float*)A(H * 4);
  w.vkq = (float*)A(H * 4);
  w.cb = (float*)A(4);
  w.cvs = (float*)A(H6 * 4);
  w.ch0s = (float*)A(H6 * 4);
  w.cvg = (float*)A(H3 * 4);
  w.chg0 = (float*)A(H3 * 4);
  w.ghs0 = (float*)A(H6 * 4);
  w.Ms = (float*)A((size_t)H6 * H * 4);
  w.Mg = (float*)A((size_t)H3 * H * 4);
  {
    void* r1 = A((size_t)GG * H6 * 4);  // max(gi_d [GG*H3], GIS [GG*H6])
    w.gi_d = (float*)r1;
    w.GIS = (float*)r1;
  }
  w.dialogue = (float*)A((size_t)GG * H * 4);
  w.U = (float*)A((size_t)GG * H * 4);
  w.cvec = (float*)A(GG * 4);
  w.GIG = (float*)A((size_t)GG * H3 * 4);
  w.gh_dbuf = (float*)A((size_t)2 * BB * H3 * 4);
  w.sp_global = (float*)A((size_t)BB * H2 * 4);
  w.op_buf = (float*)A((size_t)SS * H * 4);
  w.comb_gi = (float*)A(H3 * 4);
  w.comb_gh = (float*)A(H3 * 4);
  w.comb_si = (float*)A(H6 * 4);
  w.comb_sh = (float*)A(H6 * 4);
  w.scores_buf = (float*)A(SS * 4);
  w.probs_buf = (float*)A((size_t)GG * SS * 4);
  w.h_buf = (float*)A((size_t)GG * H2 * 4);
  w.Wbuf = (float*)A((size_t)GG * H * 4);
  w.AO = (float*)A((size_t)GG * H * 4);
  w.out_op = (float*)d_out;
  w.out_spop = (float*)d_out + (size_t)GG * H;

  hipFuncSetAttribute((const void*)coop_main, hipFuncAttributeMaxDynamicSharedMemorySize, DYN_LDS);

  hipMemsetAsync(w.flags1, 0, NWG * 16 * 4, stream);
  hipMemsetAsync(w.go1, 0, 64, stream);
  hipMemsetAsync(w.flags2, 0, NWG * 16 * 4, stream);
  hipMemsetAsync(w.go2, 0, 64, stream);

  const long NG = (long)H3 * H;
  prep1_k<<<(int)((NG + 2 * H + 1 + NT - 1) / NT), NT, 0, stream>>>(in, w);
  prep2_k<<<(H6 + H3 + H6 + 3) / 4, NT, 0, stream>>>(in, w);

  // Mqk = wq^T @ wk
  gemm_k<<<dim3(H / 64, H / 64), NT, 0, stream>>>(in.wq, 1, H, in.wk, H, w.Mqk, H, H, H);
  // Ms = s_wihA @ wv ; Mg = g_wihA @ wv
  mgemm_k<<<dim3(H / 128, H6 / 128), NT, 0, stream>>>(in.s_wih, H2, nullptr, in.wv, H, 0, nullptr, w.Ms, H, H);
  mgemm_k<<<dim3(H / 128, H3 / 128), NT, 0, stream>>>(in.g_wih, H3, nullptr, in.wv, H, 0, nullptr, w.Mg, H, H);
  // gi_d = emb[inputs] @ d_wih^T + d_bih
  mgemm_k<<<dim3(H3 / 128, GG / 128), NT, 0, stream>>>(in.emb, H, in.inputs, in.d_wih, H, 1, in.d_bih, w.gi_d, H3, H);
  coop_rnnD<<<NWG, NT, 0, stream>>>(in, w);

  // U = dialogue @ Mqk ; GIS = dialogue @ s_wihB^T + s_bih ; GIG = dialogue @ Gsum^T + g_bih
  mgemm_k<<<dim3(H / 128, GG / 128), NT, 0, stream>>>(w.dialogue, H, nullptr, w.Mqk, H, 0, nullptr, w.U, H, H);
  mgemm_k<<<dim3(H6 / 128, GG / 128), NT, 0, stream>>>(w.dialogue, H, nullptr, in.s_wih + H, H2, 1, in.s_bih, w.GIS, H6, H);
  mgemm_k<<<dim3(H3 / 128, GG / 128), NT, 0, stream>>>(w.dialogue, H, nullptr, w.Gsum, H, 1, in.g_bih, w.GIG, H3, H);
  fixup_u_k<<<(GG * H + NT - 1) / NT, NT, 0, stream>>>(w);
  cvec_k<<<GG / 4, NT, 0, stream>>>(w);

  coop_main<<<NWG, NT, DYN_LDS, stream>>>(in, w);

  epi_W_k<<<GG, NT, 0, stream>>>(w);
  // AO = Wbuf @ wv^T + bv
  mgemm_k<<<dim3(H / 128, GG / 128), NT, 0, stream>>>(w.Wbuf, H, nullptr, in.wv, H, 1, in.bv, w.AO, H, H);
  assemble_k<<<(int)(((long)GG * H2 + NT - 1) / NT), NT, 0, stream>>>(in, w);
}

// Round 5
// 21228.555 us; speedup vs baseline: 5.1840x; 1.2095x over previous
//
#include <hip/hip_runtime.h>
#include <hip/hip_bf16.h>

typedef unsigned int uint32;
typedef unsigned short u16;
typedef unsigned long long u64;
typedef __attribute__((ext_vector_type(8))) short s16x8;
typedef __attribute__((ext_vector_type(4))) float f32x4;

#define H    768
#define H2   1536
#define H3   2304
#define H6   4608
#define BB   8
#define SS   128
#define GG   1024
#define NWG  256
#define NT   256
#define INVSCALE 0.036084391824351615f
#define SPIN_LIMIT (1 << 16)
#define DYN_LDS 163392

struct IN {
  const int *chat_ids, *speaker_info, *inputs;
  const float *emb, *d_wih, *d_whh, *d_bih, *d_bhh;
  const float *g_wih, *g_whh, *g_bih, *g_bhh;
  const float *s_wih, *s_whh, *s_bih, *s_bhh;
  const float *wq, *bq, *wk, *bk, *wv, *bv;
  const float *h0, *d_h0, *attn_h;
};

struct WS {
  int *flags1, *go1, *flags2, *go2;
  float *Mqk, *Gsum;
  float *cu, *vkq, *cb, *cvs, *ch0s, *cvg, *chg0, *ghs0;
  float *Ms, *Mg;
  float *gi_d, *GIS;           // aliased region
  float *dialogue, *U, *cvec, *GIG;
  float *gh_dbuf;              // [2][BB][H3]
  float *sp_global;            // [8][H2]
  float *op_buf;               // [SS][H]
  float *op_vec;               // [H]  broadcast op_{g}
  float *h_vec;                // [H2] broadcast h_new_{g}
  float *scores_buf, *probs_buf;
  float *h_buf, *Wbuf, *AO;
  float *out_op, *out_spop;
};

__device__ inline float sigm(float x) { return 1.f / (1.f + expf(-x)); }

__device__ inline u16 f2bf(float v) {
  __hip_bfloat16 b = __float2bfloat16(v);
  return *reinterpret_cast<u16*>(&b);
}
__device__ inline uint32 pack2bf(float a, float b) {
  return (uint32)f2bf(a) | ((uint32)f2bf(b) << 16);
}

// ---- agent-scope write-through accessors (bypass non-coherent per-XCD L2) ----
__device__ inline float2 ld2(const float* p) { return *(const float2*)p; }
__device__ inline float2 ald2(const float* p) {
  u64 v = __hip_atomic_load((const u64*)p, __ATOMIC_RELAXED, __HIP_MEMORY_SCOPE_AGENT);
  union { u64 u; float2 f; } c; c.u = v; return c.f;
}
__device__ inline void ast2(float* p, float2 f) {
  union { u64 u; float2 f; } c; c.f = f;
  __hip_atomic_store((u64*)p, c.u, __ATOMIC_RELAXED, __HIP_MEMORY_SCOPE_AGENT);
}
__device__ inline float ald(const float* p) {
  return __hip_atomic_load(p, __ATOMIC_RELAXED, __HIP_MEMORY_SCOPE_AGENT);
}
__device__ inline void ast(float* p, float v) {
  __hip_atomic_store(p, v, __ATOMIC_RELAXED, __HIP_MEMORY_SCOPE_AGENT);
}

// ---- fence-free hierarchical grid barrier ----
__device__ inline void gbar(int* flags, int* go, int epoch, int& dead) {
  int bail = 0;
  __syncthreads();
  if (!dead) {
    if (blockIdx.x == 0) {
      if (threadIdx.x > 0 && threadIdx.x < NWG) {
        int spins = 0;
        while (__hip_atomic_load(&flags[threadIdx.x * 16], __ATOMIC_RELAXED, __HIP_MEMORY_SCOPE_AGENT) < epoch) {
          __builtin_amdgcn_s_sleep(2);
          if (++spins > SPIN_LIMIT) { bail = 1; break; }
        }
      }
    } else if (threadIdx.x == 0) {
      __hip_atomic_store(&flags[blockIdx.x * 16], epoch, __ATOMIC_RELAXED, __HIP_MEMORY_SCOPE_AGENT);
    }
  }
  dead |= __syncthreads_or(bail);
  bail = 0;
  if (!dead) {
    if (blockIdx.x == 0) {
      if (threadIdx.x == 0)
        __hip_atomic_store(go, epoch, __ATOMIC_RELAXED, __HIP_MEMORY_SCOPE_AGENT);
    } else if (threadIdx.x == 0) {
      int spins = 0;
      while (__hip_atomic_load(go, __ATOMIC_RELAXED, __HIP_MEMORY_SCOPE_AGENT) < epoch) {
        __builtin_amdgcn_s_sleep(2);
        if (++spins > SPIN_LIMIT) { bail = 1; break; }
      }
    }
  }
  dead |= __syncthreads_or(bail);
  asm volatile("" ::: "memory");
}

// ---- register-x dot helpers ----
template <int NI>
__device__ inline float dotr(const u16* wcol, const float2* xr) {
  const uint32* wp = (const uint32*)wcol;
  int l = threadIdx.x & 63;
  float acc = 0.f;
  #pragma unroll
  for (int i = 0; i < NI; i++) {
    uint32 u = wp[i * 64 + l];
    acc = fmaf(xr[i].x, __uint_as_float(u << 16),
          fmaf(xr[i].y, __uint_as_float(u & 0xffff0000u), acc));
  }
  #pragma unroll
  for (int o = 32; o > 0; o >>= 1) acc += __shfl_down(acc, o);
  return acc;  // valid on lane 0
}
template <int NI>
__device__ inline void loadx_lds(float2* xr, const float* x) {
  int l = threadIdx.x & 63;
  #pragma unroll
  for (int i = 0; i < NI; i++) xr[i] = ld2(x + 2 * (i * 64 + l));
}
template <int NI>
__device__ inline void loadx_atm(float2* xr, const float* x) {
  int l = threadIdx.x & 63;
  #pragma unroll
  for (int i = 0; i < NI; i++) xr[i] = ald2(x + 2 * (i * 64 + l));
}

// ================= prep kernels =================

__global__ __launch_bounds__(NT) void prep1_k(IN in, WS w) {
  long i = (long)blockIdx.x * NT + threadIdx.x;
  const long NG = (long)H3 * H;
  if (i < NG) {
    long n = i / H, k = i - n * H;
    w.Gsum[i] = in.g_wih[n * H3 + H + k] + in.g_wih[n * H3 + 2 * H + k];
  } else if (i < NG + H) {
    int m = (int)(i - NG);
    float a = 0.f;
    for (int t = 0; t < H; t++) a = fmaf(in.bq[t], in.wk[(long)t * H + m], a);
    w.cu[m] = a;
  } else if (i < NG + 2 * H) {
    int m = (int)(i - NG - H);
    float a = 0.f;
    for (int t = 0; t < H; t++) a = fmaf(in.bk[t], in.wq[(long)t * H + m], a);
    w.vkq[m] = a;
  } else if (i == NG + 2 * H) {
    float a = 0.f;
    for (int t = 0; t < H; t++) a = fmaf(in.bk[t], in.bq[t], a);
    w.cb[0] = a;
  }
}

__global__ __launch_bounds__(NT) void prep2_k(IN in, WS w) {
  int wid = blockIdx.x * (NT / 64) + (threadIdx.x >> 6);
  int l = threadIdx.x & 63;
  const int R1 = H6, R2 = H6 + H3, R3 = H6 + H3 + H6;
  if (wid < R1) {
    const float* row = in.s_wih + (long)wid * H2;
    float a = 0.f, c = 0.f;
    for (int i = l; i < H; i += 64) { float rv = row[i]; a = fmaf(in.bv[i], rv, a); c = fmaf(in.attn_h[i], rv, c); }
    #pragma unroll
    for (int o = 32; o > 0; o >>= 1) { a += __shfl_down(a, o); c += __shfl_down(c, o); }
    if (l == 0) { w.cvs[wid] = a; w.ch0s[wid] = c; }
  } else if (wid < R2) {
    int k = wid - R1;
    const float* row = in.g_wih + (long)k * H3;
    float a = 0.f, c = 0.f;
    for (int i = l; i < H; i += 64) { float rv = row[i]; a = fmaf(in.bv[i], rv, a); c = fmaf(in.attn_h[i], rv, c); }
    #pragma unroll
    for (int o = 32; o > 0; o >>= 1) { a += __shfl_down(a, o); c += __shfl_down(c, o); }
    if (l == 0) { w.cvg[k] = a; w.chg0[k] = c; }
  } else if (wid < R3) {
    int k = wid - R2;
    const float* row = in.s_whh + (long)k * H2;
    float a = 0.f;
    for (int i = l; i < H2; i += 64) a = fmaf(in.h0[i], row[i], a);
    #pragma unroll
    for (int o = 32; o > 0; o >>= 1) a += __shfl_down(a, o);
    if (l == 0) w.ghs0[k] = a + in.s_bhh[k];
  }
}

// ---- f32 GEMM (kept only for Mqk: col-major A) ----
__global__ __launch_bounds__(NT) void gemm_k(const float* A, long sAm, long sAk,
                                             const float* B, long sBk,
                                             float* C, int M, int N, int K) {
  __shared__ float As[16][65];
  __shared__ float Bs[16][65];
  int m0 = blockIdx.y * 64, n0 = blockIdx.x * 64;
  int tid = threadIdx.x;
  int tx = tid & 15, ty = tid >> 4;
  float acc[4][4] = {};
  for (int k0 = 0; k0 < K; k0 += 16) {
    {
      int m = tid & 63, kb = tid >> 6;
      for (int p = 0; p < 4; p++) {
        int k = kb + p * 4;
        As[k][m] = A[(long)(m0 + m) * sAm + (long)(k0 + k) * sAk];
      }
    }
    {
      int n = tid & 63, kb = tid >> 6;
      for (int p = 0; p < 4; p++) {
        int k = kb + p * 4;
        Bs[k][n] = B[(long)(k0 + k) * sBk + (n0 + n)];
      }
    }
    __syncthreads();
    #pragma unroll
    for (int k = 0; k < 16; k++) {
      float a[4], b[4];
      #pragma unroll
      for (int i = 0; i < 4; i++) a[i] = As[k][ty * 4 + i];
      #pragma unroll
      for (int j = 0; j < 4; j++) b[j] = Bs[k][tx * 4 + j];
      #pragma unroll
      for (int i = 0; i < 4; i++)
        #pragma unroll
        for (int j = 0; j < 4; j++) acc[i][j] = fmaf(a[i], b[j], acc[i][j]);
    }
    __syncthreads();
  }
  for (int i = 0; i < 4; i++)
    for (int j = 0; j < 4; j++) {
      int m = m0 + ty * 4 + i, n = n0 + tx * 4 + j;
      C[(long)m * N + n] = acc[i][j];
    }
}

// ---- MFMA bf16 GEMM ----
__global__ __launch_bounds__(NT) void mgemm_k(const float* A, long sAm, const int* gather,
                                              const float* B, long sB, int bColMajor,
                                              const float* bias, float* C, int N, int K) {
  __shared__ u16 Al[128 * 40];
  __shared__ u16 Bl[128 * 40];
  int tid = threadIdx.x;
  int n0 = blockIdx.x * 128, m0 = blockIdx.y * 128;
  int l = tid & 63, wv = tid >> 6;
  int wr = wv >> 1, wc = wv & 1;
  f32x4 acc[4][4] = {};
  long arow = gather ? (long)gather[m0 + (tid >> 1)] : (long)(m0 + (tid >> 1));
  for (int k0 = 0; k0 < K; k0 += 32) {
    __syncthreads();
    {
      int r = tid >> 1, half = tid & 1;
      const float* src = A + arow * sAm + k0 + half * 16;
      uint32* dst = (uint32*)(Al + r * 40 + half * 16);
      #pragma unroll
      for (int j = 0; j < 8; j++) dst[j] = pack2bf(src[2 * j], src[2 * j + 1]);
    }
    if (bColMajor) {
      int n = tid >> 1, half = tid & 1;
      const float* src = B + (long)(n0 + n) * sB + k0 + half * 16;
      uint32* dst = (uint32*)(Bl + n * 40 + half * 16);
      #pragma unroll
      for (int j = 0; j < 8; j++) dst[j] = pack2bf(src[2 * j], src[2 * j + 1]);
    } else {
      int kk = tid & 31, nb = tid >> 5;
      const float* src = B + (long)(k0 + kk) * sB + n0 + nb * 16;
      #pragma unroll
      for (int j = 0; j < 16; j++) Bl[(nb * 16 + j) * 40 + kk] = f2bf(src[j]);
    }
    __syncthreads();
    s16x8 af[4], bf[4];
    #pragma unroll
    for (int i = 0; i < 4; i++) {
      af[i] = *(const s16x8*)(Al + (wr * 64 + i * 16 + (l & 15)) * 40 + (l >> 4) * 8);
      bf[i] = *(const s16x8*)(Bl + (wc * 64 + i * 16 + (l & 15)) * 40 + (l >> 4) * 8);
    }
    #pragma unroll
    for (int i = 0; i < 4; i++)
      #pragma unroll
      for (int j = 0; j < 4; j++)
        acc[i][j] = __builtin_amdgcn_mfma_f32_16x16x32_bf16(af[i], bf[j], acc[i][j], 0, 0, 0);
  }
  #pragma unroll
  for (int i = 0; i < 4; i++)
    #pragma unroll
    for (int j = 0; j < 4; j++) {
      int n = n0 + wc * 64 + j * 16 + (l & 15);
      int mb = m0 + wr * 64 + i * 16 + ((l >> 4) << 2);
      float bb = bias ? bias[n] : 0.f;
      #pragma unroll
      for (int r = 0; r < 4; r++)
        C[(long)(mb + r) * N + n] = acc[i][j][r] + bb;
    }
}

// ================= sequential kernels =================

__global__ __launch_bounds__(NT) void coop_rnnD(IN in, WS w) {
  __shared__ u16 wD[9 * H];
  __shared__ float hB[BB][H];
  int tid = threadIdx.x, wg = blockIdx.x;
  int c0 = wg * 9;
  int l = tid & 63, wv = tid >> 6;
  for (int i = tid; i < 9 * H; i += NT)
    wD[i] = f2bf(in.d_whh[(long)(c0 + i / H) * H + (i % H)]);
  for (int i = tid; i < BB * H; i += NT) ((float*)hB)[i] = 0.f;
  __syncthreads();
  int epoch = 1, dead = 0;
  for (int t = 0; t < SS; t++) {
    if (t > 0) {
      float* ghb = w.gh_dbuf + (size_t)(t & 1) * BB * H3;
      for (int bi = 0; bi < 2; bi++) {
        int b = wv * 2 + bi;
        float2 xr[6];
        loadx_lds<6>(xr, hB[b]);
        for (int j = 0; j < 9; j++) {
          float val = dotr<6>(wD + j * H, xr);
          if (l == 0) ast(ghb + (long)b * H3 + c0 + j, val + in.d_bhh[c0 + j]);
        }
      }
      gbar(w.flags1, w.go1, epoch++, dead);
    }
    const float* ghb = w.gh_dbuf + (size_t)(t & 1) * BB * H3;
    for (int pc = tid; pc < BB * H / 2; pc += NT) {
      int b = pc / (H / 2), k = 2 * (pc - b * (H / 2));
      const float* gi = w.gi_d + ((long)(b * SS + t)) * H3;
      float2 gr = ld2(gi + k), gz = ld2(gi + H + k), gn = ld2(gi + 2 * H + k);
      float2 hr, hz, hn2;
      if (t == 0) {
        hr = ld2(in.d_bhh + k); hz = ld2(in.d_bhh + H + k); hn2 = ld2(in.d_bhh + 2 * H + k);
      } else {
        const float* gb = ghb + (long)b * H3;
        hr = ald2(gb + k); hz = ald2(gb + H + k); hn2 = ald2(gb + 2 * H + k);
      }
      float p0 = (t == 0) ? 0.f : hB[b][k], p1 = (t == 0) ? 0.f : hB[b][k + 1];
      float r0 = sigm(gr.x + hr.x), r1 = sigm(gr.y + hr.y);
      float z0 = sigm(gz.x + hz.x), z1 = sigm(gz.y + hz.y);
      float n0 = tanhf(gn.x + r0 * hn2.x), n1 = tanhf(gn.y + r1 * hn2.y);
      float h0v = (1.f - z0) * n0 + z0 * p0, h1v = (1.f - z1) * n1 + z1 * p1;
      hB[b][k] = h0v; hB[b][k + 1] = h1v;
      if (wg == 0) *(float2*)(w.dialogue + ((long)(b * SS + t)) * H + k) = make_float2(h0v, h1v);
    }
    __syncthreads();
  }
}

// Distributed-gate cooperative main loop.
// WG wg owns g-GRU OUTPUT cols [wg*3, wg*3+3) and s-GRU OUTPUT cols [wg*6, wg*6+6).
// Gate-row mapping: s: rrS(j) = (j/6)*H2 + c0s + j%6 (j<18); g: rrG(j) = (j/3)*H + c0g3 + j%3 (j<9).
__global__ __launch_bounds__(NT) void coop_main(IN in, WS w) {
  extern __shared__ char Lds[];
  u16*   wShh  = (u16*)(Lds + 0);        // [18][1536] s_whh gate-rows
  u16*   wGab  = (u16*)(Lds + 55296);    // [9][1536]  g_wih AB gate-rows
  u16*   wMs   = (u16*)(Lds + 82944);    // [18][768]  Ms gate-rows
  u16*   wMg   = (u16*)(Lds + 110592);   // [9][768]   Mg gate-rows
  u16*   wGhh  = (u16*)(Lds + 124416);   // [9][768]   g_whh gate-rows
  float* OPMSl = (float*)(Lds + 138240); // [128][19] (padded stride)
  float* OPMGl = (float*)(Lds + 147968); // [128][9]
  float* h_lds = (float*)(Lds + 152576); // [1536] broadcast h_new
  float* op_lds= (float*)(Lds + 158720); // [768]  broadcast op
  float* sc_l  = (float*)(Lds + 161792); // [128]
  float* pr_l  = (float*)(Lds + 162304); // [128]
  float* red   = (float*)(Lds + 162816); // [32]
  float* spc   = (float*)(Lds + 162944); // [8][6] speaker states, own cols
  float* loc_si  = (float*)(Lds + 163136); // [18] attn input-side (s)
  float* loc_ghs = (float*)(Lds + 163208); // [18] gh_s (hidden side, s)
  float* loc_gw  = (float*)(Lds + 163280); // [9]  attn input-side (g)
  float* loc_ghg = (float*)(Lds + 163316); // [9]  gh_g (hidden side, g)
  float* loc_gih = (float*)(Lds + 163352); // [9]  gig_h dots

  int tid = threadIdx.x, wg = blockIdx.x;
  int l = tid & 63, wv = tid >> 6;
  int c0s = wg * 6, c0g3 = wg * 3;
  auto rrS = [&](int j) { return (j / 6) * H2 + c0s + (j % 6); };
  auto rrG = [&](int j) { return (j / 3) * H + c0g3 + (j % 3); };

  for (int i = tid; i < 18 * H2; i += NT) { int j = i / H2, k = i - j * H2; wShh[i] = f2bf(in.s_whh[(long)rrS(j) * H2 + k]); }
  for (int i = tid; i < 9 * H2;  i += NT) { int j = i / H2, k = i - j * H2; wGab[i] = f2bf(in.g_wih[(long)rrG(j) * H3 + k]); }
  for (int i = tid; i < 18 * H;  i += NT) { int j = i / H,  k = i - j * H;  wMs[i]  = f2bf(w.Ms[(long)rrS(j) * H + k]); }
  for (int i = tid; i < 9 * H;   i += NT) { int j = i / H,  k = i - j * H;  wMg[i]  = f2bf(w.Mg[(long)rrG(j) * H + k]); }
  for (int i = tid; i < 9 * H;   i += NT) { int j = i / H,  k = i - j * H;  wGhh[i] = f2bf(in.g_whh[(long)rrG(j) * H + k]); }
  for (int i = tid; i < H; i += NT) op_lds[i] = in.d_h0[i];
  __syncthreads();

  int epoch = 1, dead = 0;

  for (int g = 0; g < GG; g++) {
    int s = g & 127, b = g >> 7;
    int spk_cur = in.speaker_info[in.chat_ids[b] * SS + s];

    // ---- prefetch GIS slice for the s-gate (issued early, used after stage2) ----
    float gis_r = 0.f, gis_z = 0.f, gis_n = 0.f;
    if (tid < 6) {
      const float* GISr = w.GIS + (long)g * H6;
      int c = c0s + tid;
      gis_r = GISr[c]; gis_z = GISr[H2 + c]; gis_n = GISr[2 * H2 + c];
    }

    // ---- load broadcast op_{g-1} ----
    if (g > 0) {
      for (int pc = tid; pc < H / 2; pc += NT) {
        float2 v = ald2(w.op_vec + 2 * pc);
        op_lds[2 * pc] = v.x; op_lds[2 * pc + 1] = v.y;
      }
    }
    __syncthreads();

    // ---- softmax (redundant; cheap) ----
    if (s >= 1) {
      if (tid <= s - 2) sc_l[tid] = ald(w.scores_buf + tid);
      const float* Ug = w.U + (long)g * H;
      float part = 0.f;
      for (int pc = tid; pc < H / 2; pc += NT) {
        float2 u = ld2(Ug + 2 * pc);
        part = fmaf(op_lds[2 * pc], u.x, fmaf(op_lds[2 * pc + 1], u.y, part));
      }
      #pragma unroll
      for (int o = 32; o > 0; o >>= 1) part += __shfl_down(part, o);
      if (l == 0) red[wv] = part;
      __syncthreads();
      if (tid == 0) {
        float cv = w.cvec[g];
        sc_l[s - 1] = red[0] + red[1] + red[2] + red[3] + cv;
        sc_l[s] = cv;
      }
      __syncthreads();
      float v = (tid <= s) ? sc_l[tid] : -3.0e38f;
      float m = v;
      #pragma unroll
      for (int o = 32; o > 0; o >>= 1) m = fmaxf(m, __shfl_xor(m, o));
      if (l == 0) red[4 + wv] = m;
      __syncthreads();
      m = fmaxf(fmaxf(red[4], red[5]), fmaxf(red[6], red[7]));
      float e = (tid <= s) ? expf(v - m) : 0.f;
      float su = e;
      #pragma unroll
      for (int o = 32; o > 0; o >>= 1) su += __shfl_xor(su, o);
      if (l == 0) red[8 + wv] = su;
      __syncthreads();
      su = red[8] + red[9] + red[10] + red[11];
      if (tid < SS) pr_l[tid] = (tid <= s - 1) ? e / su : 0.f;
      __syncthreads();
      if (wg == 0 && tid < SS) w.probs_buf[(long)g * SS + tid] = pr_l[tid];
    } else {
      if (tid < SS) pr_l[tid] = 0.f;
      __syncthreads();
      if (wg == 0 && tid < SS) w.probs_buf[(long)g * SS + tid] = 0.f;
    }

    // ---- PH1: attn dots + gh_g + s-gate (owner only) ----
    if (s == 0) {
      if (tid < 18) loc_si[tid] = w.ch0s[rrS(tid)];
      else if (tid >= 32 && tid < 41) loc_gw[tid - 32] = w.chg0[rrG(tid - 32)];
      if (tid >= 64 && tid < 112) { int x = (tid - 64) / 6, t2 = (tid - 64) % 6; spc[x * 6 + t2] = in.h0[c0s + t2]; }
      if (tid >= 128 && tid < 176) {
        int x = (tid - 128) / 6, t2 = (tid - 128) % 6;
        if (x != spk_cur) ast(w.sp_global + (long)x * H2 + c0s + t2, in.h0[c0s + t2]);
      }
      if (wv == 3) {
        float2 xr[6];
        loadx_lds<6>(xr, op_lds);
        for (int j = 0; j < 9; j++) {
          float val = dotr<6>(wGhh + j * H, xr);
          if (l == 0) loc_ghg[j] = val + in.g_bhh[rrG(j)];
        }
      }
      __syncthreads();
    } else {
      float2 xr[6];
      loadx_lds<6>(xr, op_lds);
      if (wv < 2) {
        int j0 = wv * 9;
        for (int j = 0; j < 9; j++) {
          float val = dotr<6>(wMs + (j0 + j) * H, xr);
          if (l == 0) red[j0 + j] = val;
        }
      } else if (wv == 2) {
        for (int j = 0; j < 9; j++) {
          float val = dotr<6>(wMg + j * H, xr);
          if (l == 0) red[18 + j] = val;
        }
      } else {
        for (int j = 0; j < 9; j++) {
          float val = dotr<6>(wGhh + j * H, xr);
          if (l == 0) loc_ghg[j] = val + in.g_bhh[rrG(j)];
        }
      }
      __syncthreads();
      float ps1 = pr_l[s - 1];
      if (wv < 2) {
        int j0 = wv * 9;
        for (int j = 0; j < 9; j++) {
          int c = j0 + j;
          float a = 0.f;
          if (l <= s - 2) a = pr_l[l] * OPMSl[l * 19 + c];
          if (l + 64 <= s - 2) a = fmaf(pr_l[l + 64], OPMSl[(l + 64) * 19 + c], a);
          #pragma unroll
          for (int o = 32; o > 0; o >>= 1) a += __shfl_down(a, o);
          if (l == 0) {
            float nr = red[c];
            OPMSl[(s - 1) * 19 + c] = nr;
            loc_si[c] = a + ps1 * nr + w.cvs[rrS(c)];
          }
        }
      } else if (wv == 2) {
        for (int j = 0; j < 9; j++) {
          float a = 0.f;
          if (l <= s - 2) a = pr_l[l] * OPMGl[l * 9 + j];
          if (l + 64 <= s - 2) a = fmaf(pr_l[l + 64], OPMGl[(l + 64) * 9 + j], a);
          #pragma unroll
          for (int o = 32; o > 0; o >>= 1) a += __shfl_down(a, o);
          if (l == 0) {
            float nr = red[18 + j];
            OPMGl[(s - 1) * 9 + j] = nr;
            loc_gw[j] = a + ps1 * nr + w.cvg[rrG(j)];
          }
        }
      }
      __syncthreads();
    }
    // s-gate: own 6 output cols
    if (tid < 6) {
      int c = c0s + tid;
      float hprev = spc[spk_cur * 6 + tid];
      float ghr, ghz, ghn;
      if (s == 0) { ghr = w.ghs0[c]; ghz = w.ghs0[H2 + c]; ghn = w.ghs0[2 * H2 + c]; }
      else { ghr = loc_ghs[tid]; ghz = loc_ghs[6 + tid]; ghn = loc_ghs[12 + tid]; }
      float gir = gis_r + loc_si[tid];
      float giz = gis_z + loc_si[6 + tid];
      float gin = gis_n + loc_si[12 + tid];
      float r = sigm(gir + ghr), z = sigm(giz + ghz);
      float n = tanhf(gin + r * ghn);
      float hn = (1.f - z) * n + z * hprev;
      spc[spk_cur * 6 + tid] = hn;
      ast(w.h_vec + c, hn);
      ast(w.sp_global + (long)spk_cur * H2 + c, hn);
      w.h_buf[(long)g * H2 + c] = hn;
    }
    gbar(w.flags2, w.go2, epoch++, dead);

    // ---- PH2: load h_new, dots for next step, op-gate (owner only) ----
    for (int pc = tid; pc < H2 / 2; pc += NT) {
      float2 v = ald2(w.h_vec + 2 * pc);
      h_lds[2 * pc] = v.x; h_lds[2 * pc + 1] = v.y;
    }
    __syncthreads();
    {
      int g1 = g + 1, s1 = g1 & 127;
      if (wv < 2) {
        if (g1 < GG && s1 != 0) {
          int spk_next = in.speaker_info[in.chat_ids[g1 >> 7] * SS + s1];
          float2 xr[12];
          if (spk_next == spk_cur) loadx_lds<12>(xr, h_lds);
          else loadx_atm<12>(xr, w.sp_global + (long)spk_next * H2);
          int j0 = wv * 9;
          for (int j = 0; j < 9; j++) {
            float val = dotr<12>(wShh + (j0 + j) * H2, xr);
            if (l == 0) loc_ghs[j0 + j] = val + in.s_bhh[rrS(j0 + j)];
          }
        }
      } else if (wv == 2) {
        float2 xr[12];
        loadx_lds<12>(xr, h_lds);
        for (int j = 0; j < 9; j++) {
          float val = dotr<12>(wGab + j * H2, xr);
          if (l == 0) loc_gih[j] = val;
        }
      } else {
        if (g1 < GG && s1 >= 2 && wg < s1 - 1) {
          const float* opr = w.op_buf + (long)wg * H;
          const float* Ur = w.U + (long)g1 * H;
          float a = 0.f;
          #pragma unroll
          for (int i0 = 0; i0 < 6; i0++) {
            int idx = i0 * 64 + l;
            float2 xa = ald2(opr + 2 * idx);
            float2 xb = ld2(Ur + 2 * idx);
            a = fmaf(xa.x, xb.x, fmaf(xa.y, xb.y, a));
          }
          #pragma unroll
          for (int o = 32; o > 0; o >>= 1) a += __shfl_down(a, o);
          if (l == 0) ast(w.scores_buf + wg, a + w.cvec[g1]);
        }
      }
    }
    __syncthreads();
    // op-gate: own 3 output cols
    if (tid < 3) {
      int c = c0g3 + tid;
      const float* GIGr = w.GIG + (long)g * H3;
      float gir = GIGr[c]         + loc_gw[tid]     + loc_gih[tid];
      float giz = GIGr[H + c]     + loc_gw[3 + tid] + loc_gih[3 + tid];
      float gin = GIGr[2 * H + c] + loc_gw[6 + tid] + loc_gih[6 + tid];
      float r = sigm(gir + loc_ghg[tid]);
      float z = sigm(giz + loc_ghg[3 + tid]);
      float n = tanhf(gin + r * loc_ghg[6 + tid]);
      float o = (1.f - z) * n + z * op_lds[c];
      ast(w.op_vec + c, o);
      ast(w.op_buf + (long)s * H + c, o);
      w.out_op[(long)g * H + c] = o;
    }
    gbar(w.flags2, w.go2, epoch++, dead);
  }
}

// ================= epilogue =================

__global__ __launch_bounds__(NT) void fixup_u_k(WS w) {
  long i = (long)blockIdx.x * NT + threadIdx.x;
  if (i < (long)GG * H) {
    int m = (int)(i % H);
    w.U[i] = (w.U[i] + w.cu[m]) * INVSCALE;
  }
}

__global__ __launch_bounds__(NT) void cvec_k(WS w) {
  int g = blockIdx.x * 4 + (threadIdx.x >> 6);
  int l = threadIdx.x & 63;
  const float* d = w.dialogue + (long)g * H;
  float p = 0.f;
  for (int i = l; i < H; i += 64) p = fmaf(d[i], w.vkq[i], p);
  #pragma unroll
  for (int o = 32; o > 0; o >>= 1) p += __shfl_down(p, o);
  if (l == 0) w.cvec[g] = (p + w.cb[0]) * INVSCALE;
}

__global__ __launch_bounds__(NT) void epi_W_k(WS w) {
  int g = blockIdx.x, b = g >> 7;
  __shared__ float pl[SS];
  if (threadIdx.x < SS) pl[threadIdx.x] = w.probs_buf[(long)g * SS + threadIdx.x];
  __syncthreads();
  const float* opb = w.out_op + (long)b * SS * H;
  for (int n = threadIdx.x; n < H; n += NT) {
    float acc = 0.f;
    for (int j = 0; j < SS; j++) acc = fmaf(pl[j], opb[(long)j * H + n], acc);
    w.Wbuf[(long)g * H + n] = acc;
  }
}

__global__ __launch_bounds__(NT) void assemble_k(IN in, WS w) {
  long idx = (long)blockIdx.x * NT + threadIdx.x;
  if (idx >= (long)GG * H2) return;
  long g = idx / H2;
  int k = (int)(idx - g * H2);
  int s = (int)(g & 127);
  float t;
  if (k < H) t = (s == 0) ? in.attn_h[k] : w.AO[g * H + k];
  else t = w.dialogue[g * H + (k - H)];
  w.out_spop[idx] = w.h_buf[idx] + t;
}

// ================= host =================

extern "C" void kernel_launch(void* const* d_in, const int* in_sizes, int n_in,
                              void* d_out, int out_size, void* d_ws, size_t ws_size,
                              hipStream_t stream) {
  IN in;
  in.chat_ids = (const int*)d_in[0];
  in.speaker_info = (const int*)d_in[1];
  in.inputs = (const int*)d_in[4];
  in.emb = (const float*)d_in[5];
  in.d_wih = (const float*)d_in[6];  in.d_whh = (const float*)d_in[7];
  in.d_bih = (const float*)d_in[8];  in.d_bhh = (const float*)d_in[9];
  in.g_wih = (const float*)d_in[10]; in.g_whh = (const float*)d_in[11];
  in.g_bih = (const float*)d_in[12]; in.g_bhh = (const float*)d_in[13];
  in.s_wih = (const float*)d_in[14]; in.s_whh = (const float*)d_in[15];
  in.s_bih = (const float*)d_in[16]; in.s_bhh = (const float*)d_in[17];
  in.wq = (const float*)d_in[18];  in.bq = (const float*)d_in[19];
  in.wk = (const float*)d_in[20];  in.bk = (const float*)d_in[21];
  in.wv = (const float*)d_in[22];  in.bv = (const float*)d_in[23];
  in.h0 = (const float*)d_in[24];  in.d_h0 = (const float*)d_in[25];
  in.attn_h = (const float*)d_in[26];

  char* base = (char*)d_ws;
  size_t off = 0;
  auto A = [&](size_t bytes) -> void* {
    size_t r = (off + 255) & ~(size_t)255;
    off = r + bytes;
    return (void*)(base + r);
  };
  WS w;
  w.flags1 = (int*)A(NWG * 16 * 4);
  w.go1 = (int*)A(64);
  w.flags2 = (int*)A(NWG * 16 * 4);
  w.go2 = (int*)A(64);
  w.Mqk = (float*)A((size_t)H * H * 4);
  w.Gsum = (float*)A((size_t)H3 * H * 4);
  w.cu = (float*)A(H * 4);
  w.vkq = (float*)A(H * 4);
  w.cb = (float*)A(4);
  w.cvs = (float*)A(H6 * 4);
  w.ch0s = (float*)A(H6 * 4);
  w.cvg = (float*)A(H3 * 4);
  w.chg0 = (float*)A(H3 * 4);
  w.ghs0 = (float*)A(H6 * 4);
  w.Ms = (float*)A((size_t)H6 * H * 4);
  w.Mg = (float*)A((size_t)H3 * H * 4);
  {
    void* r1 = A((size_t)GG * H6 * 4);  // max(gi_d [GG*H3], GIS [GG*H6])
    w.gi_d = (float*)r1;
    w.GIS = (float*)r1;
  }
  w.dialogue = (float*)A((size_t)GG * H * 4);
  w.U = (float*)A((size_t)GG * H * 4);
  w.cvec = (float*)A(GG * 4);
  w.GIG = (float*)A((size_t)GG * H3 * 4);
  w.gh_dbuf = (float*)A((size_t)2 * BB * H3 * 4);
  w.sp_global = (float*)A((size_t)BB * H2 * 4);
  w.op_buf = (float*)A((size_t)SS * H * 4);
  w.op_vec = (float*)A(H * 4);
  w.h_vec = (float*)A(H2 * 4);
  w.scores_buf = (float*)A(SS * 4);
  w.probs_buf = (float*)A((size_t)GG * SS * 4);
  w.h_buf = (float*)A((size_t)GG * H2 * 4);
  w.Wbuf = (float*)A((size_t)GG * H * 4);
  w.AO = (float*)A((size_t)GG * H * 4);
  w.out_op = (float*)d_out;
  w.out_spop = (float*)d_out + (size_t)GG * H;

  hipFuncSetAttribute((const void*)coop_main, hipFuncAttributeMaxDynamicSharedMemorySize, DYN_LDS);

  hipMemsetAsync(w.flags1, 0, NWG * 16 * 4, stream);
  hipMemsetAsync(w.go1, 0, 64, stream);
  hipMemsetAsync(w.flags2, 0, NWG * 16 * 4, stream);
  hipMemsetAsync(w.go2, 0, 64, stream);

  const long NG = (long)H3 * H;
  prep1_k<<<(int)((NG + 2 * H + 1 + NT - 1) / NT), NT, 0, stream>>>(in, w);
  prep2_k<<<(H6 + H3 + H6 + 3) / 4, NT, 0, stream>>>(in, w);

  // Mqk = wq^T @ wk
  gemm_k<<<dim3(H / 64, H / 64), NT, 0, stream>>>(in.wq, 1, H, in.wk, H, w.Mqk, H, H, H);
  // Ms = s_wihA @ wv ; Mg = g_wihA @ wv
  mgemm_k<<<dim3(H / 128, H6 / 128), NT, 0, stream>>>(in.s_wih, H2, nullptr, in.wv, H, 0, nullptr, w.Ms, H, H);
  mgemm_k<<<dim3(H / 128, H3 / 128), NT, 0, stream>>>(in.g_wih, H3, nullptr, in.wv, H, 0, nullptr, w.Mg, H, H);
  // gi_d = emb[inputs] @ d_wih^T + d_bih
  mgemm_k<<<dim3(H3 / 128, GG / 128), NT, 0, stream>>>(in.emb, H, in.inputs, in.d_wih, H, 1, in.d_bih, w.gi_d, H3, H);
  coop_rnnD<<<NWG, NT, 0, stream>>>(in, w);

  // U = dialogue @ Mqk ; GIS = dialogue @ s_wihB^T + s_bih ; GIG = dialogue @ Gsum^T + g_bih
  mgemm_k<<<dim3(H / 128, GG / 128), NT, 0, stream>>>(w.dialogue, H, nullptr, w.Mqk, H, 0, nullptr, w.U, H, H);
  mgemm_k<<<dim3(H6 / 128, GG / 128), NT, 0, stream>>>(w.dialogue, H, nullptr, in.s_wih + H, H2, 1, in.s_bih, w.GIS, H6, H);
  mgemm_k<<<dim3(H3 / 128, GG / 128), NT, 0, stream>>>(w.dialogue, H, nullptr, w.Gsum, H, 1, in.g_bih, w.GIG, H3, H);
  fixup_u_k<<<(GG * H + NT - 1) / NT, NT, 0, stream>>>(w);
  cvec_k<<<GG / 4, NT, 0, stream>>>(w);

  coop_main<<<NWG, NT, DYN_LDS, stream>>>(in, w);

  epi_W_k<<<GG, NT, 0, stream>>>(w);
  // AO = Wbuf @ wv^T + bv
  mgemm_k<<<dim3(H / 128, GG / 128), NT, 0, stream>>>(w.Wbuf, H, nullptr, in.wv, H, 1, in.bv, w.AO, H, H);
  assemble_k<<<(int)(((long)GG * H2 + NT - 1) / NT), NT, 0, stream>>>(in, w);
}